// Round 7
// baseline (231.488 us; speedup 1.0000x reference)
//
#include <hip/hip_runtime.h>
#include <cstdint>
#include <cstddef>

#define D_MODEL 1024
#define HD 64
#define NH 16
#define SEQ 2048
#define NB 2

typedef __attribute__((ext_vector_type(8))) short bf8;           // 8 bf16 (4 VGPR)
typedef __attribute__((ext_vector_type(8))) unsigned short us8;
typedef __attribute__((ext_vector_type(4))) unsigned short us4;
typedef __attribute__((ext_vector_type(4))) float f4;

__device__ __forceinline__ float bf2f(unsigned short u) {
  union { unsigned int i; float f; } c; c.i = ((unsigned int)u) << 16; return c.f;
}
__device__ __forceinline__ unsigned short f2bf(float x) {
  union { float f; unsigned int i; } c; c.f = x;
  unsigned int r = (c.i + 0x7FFFu + ((c.i >> 16) & 1u)) >> 16;   // RNE
  return (unsigned short)r;
}
// packed f32x2 -> bf16x2 (RNE), single HW op
__device__ __forceinline__ unsigned int pkbf(float lo, float hi) {
  unsigned int r;
  asm("v_cvt_pk_bf16_f32 %0, %1, %2" : "=v"(r) : "v"(lo), "v"(hi));
  return r;
}
// exp2 via v_exp_f32 (D = 2^S0)
__device__ __forceinline__ float ex2(float x) {
  float r;
  asm("v_exp_f32 %0, %1" : "=v"(r) : "v"(x));
  return r;
}
__device__ __forceinline__ f4 mfma16(bf8 a, bf8 b, f4 c) {
  return __builtin_amdgcn_mfma_f32_16x16x32_bf16(a, b, c, 0, 0, 0);
}
// async global->LDS, 16B per lane; LDS dest = wave-uniform base + lane*16
__device__ __forceinline__ void gl16(const unsigned short* g, unsigned short* l) {
  __builtin_amdgcn_global_load_lds(
      (const __attribute__((address_space(1))) unsigned int*)g,
      (__attribute__((address_space(3))) unsigned int*)l, 16, 0, 0);
}

#define QSCALE (0.125f * 1.44269504088896f)   // 1/sqrt(64) * log2(e)

// ---------------- convert fp32 inputs -> bf16 (once) ----------------
__global__ __launch_bounds__(256) void convert_inputs(
    const float* __restrict__ Q, const float* __restrict__ K, const float* __restrict__ V,
    unsigned short* __restrict__ dq, unsigned short* __restrict__ dk,
    unsigned short* __restrict__ dv) {
  int z = blockIdx.z;
  const float* s = (z == 0) ? Q : (z == 1) ? K : V;
  unsigned short* d = (z == 0) ? dq : (z == 1) ? dk : dv;
  size_t i = ((size_t)blockIdx.x * 256 + threadIdx.x) * 8;
  float4 a = *reinterpret_cast<const float4*>(s + i);
  float4 b = *reinterpret_cast<const float4*>(s + i + 4);
  union { us8 v; unsigned int u[4]; } o;
  o.u[0] = pkbf(a.x, a.y); o.u[1] = pkbf(a.z, a.w);
  o.u[2] = pkbf(b.x, b.y); o.u[3] = pkbf(b.z, b.w);
  *reinterpret_cast<us8*>(d + i) = o.v;
}

// ---------------- prep: transpose + hi/lo split of the 4 weight matrices ----------------
__global__ __launch_bounds__(256) void prep_weights(
    const float* __restrict__ Wq, const float* __restrict__ Wk,
    const float* __restrict__ Wv, const float* __restrict__ Wo,
    unsigned short* __restrict__ wthi, unsigned short* __restrict__ wtlo) {
  int mat = blockIdx.z;
  const float* W = (mat == 0) ? Wq : (mat == 1) ? Wk : (mat == 2) ? Wv : Wo;
  unsigned short* oh = wthi + (size_t)mat * D_MODEL * D_MODEL;
  unsigned short* ol = wtlo + (size_t)mat * D_MODEL * D_MODEL;
  __shared__ float ls[32][33];
  int nt = blockIdx.x * 32, kt = blockIdx.y * 32;
  int i = threadIdx.x >> 5;
  int j = threadIdx.x & 31;
#pragma unroll
  for (int ii = 0; ii < 4; ++ii) {
    int r = i + ii * 8;
    ls[r][j] = W[(size_t)(kt + r) * D_MODEL + nt + j];
  }
  __syncthreads();
#pragma unroll
  for (int ii = 0; ii < 4; ++ii) {
    int r = i + ii * 8;
    float v = ls[j][r];
    if (mat == 0) v *= QSCALE;
    unsigned short h = f2bf(v);
    size_t o = (size_t)(nt + r) * D_MODEL + kt + j;
    oh[o] = h;
    ol[o] = f2bf(v - bf2f(h));
  }
}

// ---------------- unified GEMM: C = A @ W^T(hi+lo) + bias, 4 epilogues ----------------
__global__ __launch_bounds__(256, 3) void gemm_kernel(
    const unsigned short* __restrict__ A0, const unsigned short* __restrict__ A1,
    const unsigned short* __restrict__ A2,
    const unsigned short* __restrict__ wth, const unsigned short* __restrict__ wtl,
    const float* __restrict__ b0, const float* __restrict__ b1,
    const float* __restrict__ b2, const float* __restrict__ b3,
    unsigned short* __restrict__ qh, unsigned short* __restrict__ kh,
    unsigned short* __restrict__ vt, float* __restrict__ o32, int zbase) {
  int z = zbase + blockIdx.z;
  const unsigned short* A = (z == 0) ? A0 : (z == 1) ? A1 : (z == 2) ? A2 : A0;
  const unsigned short* Bh = wth + ((size_t)z << 20);
  const unsigned short* Bl = wtl + ((size_t)z << 20);
  const float* bias = (z == 0) ? b0 : (z == 1) ? b1 : (z == 2) ? b2 : b3;
  float bsc = (z == 0) ? QSCALE : 1.0f;

  int bm = blockIdx.y, bn = blockIdx.x;
  int tid = threadIdx.x, lane = tid & 63, w = tid >> 6;
  int wr = w >> 1, wc = w & 1, l16 = lane & 15, l4 = lane >> 4;

  __shared__ unsigned short As[2][128 * 32];
  __shared__ unsigned short Bsh[2][128 * 32];
  __shared__ unsigned short Bsl[2][128 * 32];

  const unsigned short* Ab = A + (size_t)(bm * 128) * D_MODEL;
  const unsigned short* Bhb = Bh + (size_t)(bn * 128) * D_MODEL;
  const unsigned short* Blb = Bl + (size_t)(bn * 128) * D_MODEL;

  int r0 = tid >> 2, g0 = tid & 3;
  int r1 = (256 + tid) >> 2, g1 = tid & 3;
  int s0 = (r0 ^ (r0 >> 2)) & 3, s1 = (r1 ^ (r1 >> 2)) & 3;
  size_t so0 = (size_t)r0 * D_MODEL + ((g0 ^ s0) * 8);
  size_t so1 = (size_t)r1 * D_MODEL + ((g1 ^ s1) * 8);
  int ld0 = (w * 64) * 8;
  int ld1 = (256 + w * 64) * 8;

  int offA[4], offB[4];
#pragma unroll
  for (int m = 0; m < 4; ++m) {
    int row = wr * 64 + m * 16 + l16;
    int sw = (row ^ (row >> 2)) & 3;
    offA[m] = row * 32 + ((l4 ^ sw)) * 8;
  }
#pragma unroll
  for (int n = 0; n < 4; ++n) {
    int row = wc * 64 + n * 16 + l16;
    int sw = (row ^ (row >> 2)) & 3;
    offB[n] = row * 32 + ((l4 ^ sw)) * 8;
  }

  f4 acc[4][4];
  const f4 zf = {0.f, 0.f, 0.f, 0.f};
#pragma unroll
  for (int m = 0; m < 4; ++m)
#pragma unroll
    for (int n = 0; n < 4; ++n) acc[m][n] = zf;

  gl16(Ab + so0, &As[0][ld0]);  gl16(Ab + so1, &As[0][ld1]);
  gl16(Bhb + so0, &Bsh[0][ld0]); gl16(Bhb + so1, &Bsh[0][ld1]);
  gl16(Blb + so0, &Bsl[0][ld0]); gl16(Blb + so1, &Bsl[0][ld1]);
  __syncthreads();

  int cur = 0;
  for (int i = 0; i < 32; ++i) {
    if (i < 31) {
      int ktn = (i + 1) * 32;
      gl16(Ab + ktn + so0, &As[cur ^ 1][ld0]);  gl16(Ab + ktn + so1, &As[cur ^ 1][ld1]);
      gl16(Bhb + ktn + so0, &Bsh[cur ^ 1][ld0]); gl16(Bhb + ktn + so1, &Bsh[cur ^ 1][ld1]);
      gl16(Blb + ktn + so0, &Bsl[cur ^ 1][ld0]); gl16(Blb + ktn + so1, &Bsl[cur ^ 1][ld1]);
    }
    bf8 a[4], bh[4], bl[4];
#pragma unroll
    for (int m = 0; m < 4; ++m)
      a[m] = *reinterpret_cast<const bf8*>(&As[cur][offA[m]]);
#pragma unroll
    for (int n = 0; n < 4; ++n) {
      bh[n] = *reinterpret_cast<const bf8*>(&Bsh[cur][offB[n]]);
      bl[n] = *reinterpret_cast<const bf8*>(&Bsl[cur][offB[n]]);
    }
#pragma unroll
    for (int m = 0; m < 4; ++m)
#pragma unroll
      for (int n = 0; n < 4; ++n) {
        acc[m][n] = mfma16(a[m], bh[n], acc[m][n]);
        acc[m][n] = mfma16(a[m], bl[n], acc[m][n]);
      }
    __syncthreads();
    cur ^= 1;
  }

#pragma unroll
  for (int n = 0; n < 4; ++n) {
    int col = bn * 128 + wc * 64 + n * 16 + l16;
    float bb = bias[col] * bsc;
#pragma unroll
    for (int m = 0; m < 4; ++m) {
      int row0 = bm * 128 + wr * 64 + m * 16 + l4 * 4;
      if (z == 0) {
#pragma unroll
        for (int r = 0; r < 4; ++r)
          qh[(size_t)(row0 + r) * D_MODEL + col] = f2bf(acc[m][n][r] + bb);
      } else if (z == 1) {
#pragma unroll
        for (int r = 0; r < 4; ++r)
          kh[(size_t)(row0 + r) * D_MODEL + col] = f2bf(acc[m][n][r] + bb);
      } else if (z == 2) {
        int bb2 = row0 >> 11, ss = row0 & (SEQ - 1);
        int hh2 = col >> 6, dd = col & 63;
        union { us4 s; uint2 u; } pk4;
        pk4.u.x = pkbf(acc[m][n][0] + bb, acc[m][n][1] + bb);
        pk4.u.y = pkbf(acc[m][n][2] + bb, acc[m][n][3] + bb);
        *reinterpret_cast<us4*>(vt + ((size_t)(bb2 * NH + hh2) * HD + dd) * SEQ + ss) = pk4.s;
      } else {
#pragma unroll
        for (int r = 0; r < 4; ++r)
          o32[(size_t)(row0 + r) * D_MODEL + col] = acc[m][n][r] + bb;
      }
    }
  }
}

// ---------------- flash attention, intra-block key-split ----------------
// 1024 blocks (3/CU, 12 waves/CU), block = 4 waves, 64 q-rows SHARED by all waves.
// Wave w handles only keys w*16..w*16+15 of each 64-key tile -> per-wave LDS read
// = 4KB/tile (4x less than r4-r6). Swapped QK^T (S^T = K*Q^T) gives C-layout
// key=l4*4+r which IS the B-frag k-layout of a K=16 MFMA; emulated with
// mfma_16x16x32 + zero-padded upper k-half -> ZERO shuffle/bpermute for PV.
// Per-wave (m,l,O) partials merged once at block end via LDS (f32 exact).
__global__ __launch_bounds__(256, 3) void attn_kernel(
    const unsigned short* __restrict__ qh, const unsigned short* __restrict__ kh,
    const unsigned short* __restrict__ vt, unsigned short* __restrict__ aout) {
  // XCD-aware bijective swizzle: each XCD gets 128 consecutive wids = 4 (b,h) sets
  int bid = blockIdx.x;
  int wid = ((bid & 7) << 7) | (bid >> 3);
  int qt = wid & 31, h = (wid >> 5) & 15, b = wid >> 9;

  int tid = threadIdx.x;
  int lane = tid & 63, w = tid >> 6;
  int l16 = lane & 15, l4 = lane >> 4;
  int l8r = lane >> 3, l8c = lane & 7;

  __shared__ unsigned short lds[16384];   // 2x4096 K + 2x4096 V^T; reused by merge

  const unsigned short* Kh = kh + (size_t)b * SEQ * D_MODEL + h * HD;
  const unsigned short* Vt = vt + (size_t)(b * NH + h) * HD * SEQ;

  // q B-frags: 4 m-blocks of 16 q (same for all waves); q = qt*64 + m*16 + l16
  bf8 qf[4][2];
#pragma unroll
  for (int m = 0; m < 4; ++m) {
    size_t qo = (size_t)(b * SEQ + qt * 64 + m * 16 + l16) * D_MODEL + h * HD + l4 * 8;
    qf[m][0] = *reinterpret_cast<const bf8*>(qh + qo);
    qf[m][1] = *reinterpret_cast<const bf8*>(qh + qo + 32);
  }
  // ones A-frag (denominator MFMA)
  bf8 ones;
#pragma unroll
  for (int j = 0; j < 8; ++j) ones[j] = (short)0x3F80;

  const f4 zf = {0.f, 0.f, 0.f, 0.f};
  f4 acc[4][4];                                  // O^T partial: [m][nt], rows d, col q=l16
  f4 accs[4] = {zf, zf, zf, zf};                 // denominators (per m)
  float mr[4] = {0.f, 0.f, 0.f, 0.f};            // running max (defer-max)
#pragma unroll
  for (int m = 0; m < 4; ++m)
#pragma unroll
    for (int nt = 0; nt < 4; ++nt) acc[m][nt] = zf;

  const int sgr = (l8c ^ l8r) * 8;   // pre-swizzled source granule
  const int sl1 = w, sl2 = w + 4;    // wave's two 1KB staging slices

  // this wave's key-strip read offsets
  const int swk = l16 & 7;
  const int kbo0 = (w * 16 + l16) * 64 + ((l4 ^ swk) << 3);
  const int kbo1 = (w * 16 + l16) * 64 + (((4 + l4) ^ swk) << 3);
  const int gv = w * 2 + (l4 >> 1);  // V granule for keys w*16 + l4*4..

  // stage tile 0
  gl16(Kh + (size_t)(8 * sl1 + l8r) * D_MODEL + sgr, &lds[0 * 4096 + sl1 * 512]);
  gl16(Kh + (size_t)(8 * sl2 + l8r) * D_MODEL + sgr, &lds[0 * 4096 + sl2 * 512]);
  gl16(Vt + (size_t)(8 * sl1 + l8r) * SEQ + sgr, &lds[8192 + sl1 * 512]);
  gl16(Vt + (size_t)(8 * sl2 + l8r) * SEQ + sgr, &lds[8192 + sl2 * 512]);
  __syncthreads();

  int cur = 0;
  for (int kv = 0; kv < SEQ / 64; ++kv) {
    if (kv < SEQ / 64 - 1) {
      int k0n = (kv + 1) * 64;
      unsigned short* kd = &lds[(cur ^ 1) * 4096];
      unsigned short* vd = &lds[8192 + (cur ^ 1) * 4096];
      gl16(Kh + (size_t)(k0n + 8 * sl1 + l8r) * D_MODEL + sgr, kd + sl1 * 512);
      gl16(Kh + (size_t)(k0n + 8 * sl2 + l8r) * D_MODEL + sgr, kd + sl2 * 512);
      gl16(Vt + (size_t)(8 * sl1 + l8r) * SEQ + k0n + sgr, vd + sl1 * 512);
      gl16(Vt + (size_t)(8 * sl2 + l8r) * SEQ + k0n + sgr, vd + sl2 * 512);
    }
    const unsigned short* khb = &lds[cur * 4096];
    const unsigned short* vlb = &lds[8192 + cur * 4096];

    // K A-frags for this wave's 16-key strip (full d=64)
    bf8 kb0 = *reinterpret_cast<const bf8*>(&khb[kbo0]);
    bf8 kb1 = *reinterpret_cast<const bf8*>(&khb[kbo1]);
    // V A-frags: per nt one b64 (keys w*16+l4*4..+3), upper k-half zero
    bf8 vb[4];
#pragma unroll
    for (int nt = 0; nt < 4; ++nt) {
      int row = nt * 16 + l16;
      int vaddr = row * 64 + ((gv ^ (l16 & 7)) << 3) + ((l4 & 1) << 2);
      uint2 vd2 = *reinterpret_cast<const uint2*>(&vlb[vaddr]);
      union { bf8 v; unsigned u[4]; } vu;
      vu.u[0] = vd2.x; vu.u[1] = vd2.y; vu.u[2] = 0; vu.u[3] = 0;
      vb[nt] = vu.v;
    }

#pragma unroll
    for (int m = 0; m < 4; ++m) {
      // swapped QK^T for this strip: S^T[key = w*16 + l4*4 + r][q = l16]
      f4 s = zf;
      s = mfma16(kb0, qf[m][0], s);
      s = mfma16(kb1, qf[m][1], s);
      // max over strip: 3-op tree + cross-l4
      float tm = fmaxf(fmaxf(s[0], s[1]), fmaxf(s[2], s[3]));
      tm = fmaxf(tm, __shfl_xor(tm, 16));
      tm = fmaxf(tm, __shfl_xor(tm, 32));
      if (__any(tm > mr[m] + 8.0f)) {          // defer-max THR=8
        float mn = fmaxf(mr[m], tm);
        float al = ex2(mr[m] - mn);
        mr[m] = mn;
        accs[m][0] *= al; accs[m][1] *= al; accs[m][2] *= al; accs[m][3] *= al;
#pragma unroll
        for (int nt = 0; nt < 4; ++nt) {
          acc[m][nt][0] *= al; acc[m][nt][1] *= al;
          acc[m][nt][2] *= al; acc[m][nt][3] *= al;
        }
      }
      // P = exp2(s - m); pack into K=16-style B-frag (upper k-half zero)
      float p0 = ex2(s[0] - mr[m]), p1 = ex2(s[1] - mr[m]);
      float p2 = ex2(s[2] - mr[m]), p3 = ex2(s[3] - mr[m]);
      union { bf8 v; unsigned u[4]; } pu;
      pu.u[0] = pkbf(p0, p1); pu.u[1] = pkbf(p2, p3); pu.u[2] = 0; pu.u[3] = 0;
      // denominator + PV (zero-padded K=16 emulation, no shuffles)
      accs[m] = mfma16(ones, pu.v, accs[m]);
#pragma unroll
      for (int nt = 0; nt < 4; ++nt)
        acc[m][nt] = mfma16(vb[nt], pu.v, acc[m][nt]);
    }
    __syncthreads();
    cur ^= 1;
  }

  // ---- block-level merge of the 4 key-split partials (exact f32 in LDS) ----
  float2* mlb = reinterpret_cast<float2*>(&lds[9000]);   // [4 waves][4 m][16 q]
  float*  Lbuf = reinterpret_cast<float*>(&lds[10500]);  // [64 q]
  float*  obuf = reinterpret_cast<float*>(lds);          // [64 d][66] padded
  if (l4 == 0) {
#pragma unroll
    for (int m = 0; m < 4; ++m)
      mlb[(w * 4 + m) * 16 + l16] = make_float2(mr[m], accs[m][0]);
  }
  __syncthreads();
#pragma unroll
  for (int m = 0; m < 4; ++m) {
    float2 p0 = mlb[(0 * 4 + m) * 16 + l16], p1 = mlb[(1 * 4 + m) * 16 + l16];
    float2 p2 = mlb[(2 * 4 + m) * 16 + l16], p3 = mlb[(3 * 4 + m) * 16 + l16];
    float M = fmaxf(fmaxf(p0.x, p1.x), fmaxf(p2.x, p3.x));
    float L = p0.y * ex2(p0.x - M) + p1.y * ex2(p1.x - M) +
              p2.y * ex2(p2.x - M) + p3.y * ex2(p3.x - M);
    float so = ex2(mr[m] - M);
#pragma unroll
    for (int nt = 0; nt < 4; ++nt) {
      acc[m][nt][0] *= so; acc[m][nt][1] *= so;
      acc[m][nt][2] *= so; acc[m][nt][3] *= so;
    }
    if (w == 0 && l4 == 0) Lbuf[m * 16 + l16] = L;
  }
  // serialized cross-wave sum into obuf
  for (int t = 0; t < 4; ++t) {
    if (w == t) {
#pragma unroll
      for (int m = 0; m < 4; ++m)
#pragma unroll
        for (int nt = 0; nt < 4; ++nt)
#pragma unroll
          for (int r = 0; r < 4; ++r) {
            int idx = (nt * 16 + l4 * 4 + r) * 66 + m * 16 + l16;
            if (t == 0) obuf[idx] = acc[m][nt][r];
            else        obuf[idx] += acc[m][nt][r];
          }
    }
    __syncthreads();
  }
  // final: normalize, transpose-read, write bf16
  {
    int q = tid >> 2, dc = (tid & 3) * 16;
    float Linv = 1.0f / Lbuf[q];
    float e[16];
#pragma unroll
    for (int j = 0; j < 16; ++j) e[j] = obuf[(dc + j) * 66 + q] * Linv;
    union { us8 v; unsigned u[4]; } o1, o2;
#pragma unroll
    for (int j = 0; j < 4; ++j) {
      o1.u[j] = pkbf(e[2 * j], e[2 * j + 1]);
      o2.u[j] = pkbf(e[8 + 2 * j], e[9 + 2 * j]);
    }
    size_t orow = (size_t)(b * SEQ + qt * 64 + q) * D_MODEL + h * HD + dc;
    *reinterpret_cast<us8*>(&aout[orow]) = o1.v;
    *reinterpret_cast<us8*>(&aout[orow + 8]) = o2.v;
  }
}

extern "C" void kernel_launch(void* const* d_in, const int* in_sizes, int n_in,
                              void* d_out, int out_size, void* d_ws, size_t ws_size,
                              hipStream_t stream) {
  const float* Q  = (const float*)d_in[0];
  const float* K  = (const float*)d_in[1];
  const float* V  = (const float*)d_in[2];
  const float* Wq = (const float*)d_in[3];
  const float* bq = (const float*)d_in[4];
  const float* Wk = (const float*)d_in[5];
  const float* bk = (const float*)d_in[6];
  const float* Wv = (const float*)d_in[7];
  const float* bv = (const float*)d_in[8];
  const float* Wo = (const float*)d_in[9];
  const float* bo = (const float*)d_in[10];
  float* out = (float*)d_out;

  // workspace (56 MB) + d_out doubles as Q/K bf16 scratch (overwritten by final GEMM)
  unsigned char* ws = (unsigned char*)d_ws;
  const size_t MB = 1024 * 1024;
  unsigned short* wthi = (unsigned short*)(ws);             // 4x W^T hi      (8 MB)
  unsigned short* wtlo = (unsigned short*)(ws + 8 * MB);    // 4x W^T lo      (8 MB)
  unsigned short* qh   = (unsigned short*)(ws + 16 * MB);   // q bf16 [B,S,D] (8 MB)
  unsigned short* kh   = (unsigned short*)(ws + 24 * MB);   // k bf16         (8 MB)
  unsigned short* vt   = (unsigned short*)(ws + 32 * MB);   // V^T [B,H,d,S]  (8 MB)
  unsigned short* ah   = (unsigned short*)(ws + 40 * MB);   // attn out bf16  (8 MB)
  unsigned short* vbf  = (unsigned short*)(ws + 48 * MB);   // V input bf16   (8 MB)
  unsigned short* qbf  = (unsigned short*)d_out;            // Q input bf16 (scratch)
  unsigned short* kbf  = (unsigned short*)d_out + 4 * MB;   // K input bf16 (scratch)

  convert_inputs<<<dim3(2048, 1, 3), 256, 0, stream>>>(Q, K, V, qbf, kbf, vbf);
  prep_weights<<<dim3(32, 32, 4), 256, 0, stream>>>(Wq, Wk, Wv, Wo, wthi, wtlo);
  gemm_kernel<<<dim3(8, 32, 3), 256, 0, stream>>>(qbf, kbf, vbf, wthi, wtlo,
                                                  bq, bk, bv, bo, qh, kh, vt, out, 0);
  attn_kernel<<<dim3(1024, 1, 1), 256, 0, stream>>>(qh, kh, vt, ah);
  gemm_kernel<<<dim3(8, 32, 1), 256, 0, stream>>>(ah, ah, ah, wthi, wtlo,
                                                  bq, bk, bv, bo, qh, kh, vt, out, 3);
}

// Round 8
// 184.949 us; speedup vs baseline: 1.2516x; 1.2516x over previous
//
#include <hip/hip_runtime.h>
#include <cstdint>
#include <cstddef>

#define D_MODEL 1024
#define HD 64
#define NH 16
#define SEQ 2048
#define NB 2

typedef __attribute__((ext_vector_type(8))) short bf8;           // 8 bf16 (4 VGPR)
typedef __attribute__((ext_vector_type(8))) unsigned short us8;
typedef __attribute__((ext_vector_type(4))) unsigned short us4;
typedef __attribute__((ext_vector_type(4))) float f4;

__device__ __forceinline__ float bf2f(unsigned short u) {
  union { unsigned int i; float f; } c; c.i = ((unsigned int)u) << 16; return c.f;
}
__device__ __forceinline__ unsigned short f2bf(float x) {
  union { float f; unsigned int i; } c; c.f = x;
  unsigned int r = (c.i + 0x7FFFu + ((c.i >> 16) & 1u)) >> 16;   // RNE
  return (unsigned short)r;
}
// packed f32x2 -> bf16x2 (RNE), single HW op
__device__ __forceinline__ unsigned int pkbf(float lo, float hi) {
  unsigned int r;
  asm("v_cvt_pk_bf16_f32 %0, %1, %2" : "=v"(r) : "v"(lo), "v"(hi));
  return r;
}
// exp2 via v_exp_f32 (D = 2^S0)
__device__ __forceinline__ float ex2(float x) {
  float r;
  asm("v_exp_f32 %0, %1" : "=v"(r) : "v"(x));
  return r;
}
__device__ __forceinline__ f4 mfma16(bf8 a, bf8 b, f4 c) {
  return __builtin_amdgcn_mfma_f32_16x16x32_bf16(a, b, c, 0, 0, 0);
}
// async global->LDS, 16B per lane; LDS dest = wave-uniform base + lane*16
__device__ __forceinline__ void gl16(const unsigned short* g, unsigned short* l) {
  __builtin_amdgcn_global_load_lds(
      (const __attribute__((address_space(1))) unsigned int*)g,
      (__attribute__((address_space(3))) unsigned int*)l, 16, 0, 0);
}

#define QSCALE (0.125f * 1.44269504088896f)   // 1/sqrt(64) * log2(e)

// ---------------- convert fp32 inputs -> bf16 (once) ----------------
__global__ __launch_bounds__(256) void convert_inputs(
    const float* __restrict__ Q, const float* __restrict__ K, const float* __restrict__ V,
    unsigned short* __restrict__ dq, unsigned short* __restrict__ dk,
    unsigned short* __restrict__ dv) {
  int z = blockIdx.z;
  const float* s = (z == 0) ? Q : (z == 1) ? K : V;
  unsigned short* d = (z == 0) ? dq : (z == 1) ? dk : dv;
  size_t i = ((size_t)blockIdx.x * 256 + threadIdx.x) * 8;
  float4 a = *reinterpret_cast<const float4*>(s + i);
  float4 b = *reinterpret_cast<const float4*>(s + i + 4);
  union { us8 v; unsigned int u[4]; } o;
  o.u[0] = pkbf(a.x, a.y); o.u[1] = pkbf(a.z, a.w);
  o.u[2] = pkbf(b.x, b.y); o.u[3] = pkbf(b.z, b.w);
  *reinterpret_cast<us8*>(d + i) = o.v;
}

// ---------------- prep: transpose + hi/lo split of the 4 weight matrices ----------------
__global__ __launch_bounds__(256) void prep_weights(
    const float* __restrict__ Wq, const float* __restrict__ Wk,
    const float* __restrict__ Wv, const float* __restrict__ Wo,
    unsigned short* __restrict__ wthi, unsigned short* __restrict__ wtlo) {
  int mat = blockIdx.z;
  const float* W = (mat == 0) ? Wq : (mat == 1) ? Wk : (mat == 2) ? Wv : Wo;
  unsigned short* oh = wthi + (size_t)mat * D_MODEL * D_MODEL;
  unsigned short* ol = wtlo + (size_t)mat * D_MODEL * D_MODEL;
  __shared__ float ls[32][33];
  int nt = blockIdx.x * 32, kt = blockIdx.y * 32;
  int i = threadIdx.x >> 5;
  int j = threadIdx.x & 31;
#pragma unroll
  for (int ii = 0; ii < 4; ++ii) {
    int r = i + ii * 8;
    ls[r][j] = W[(size_t)(kt + r) * D_MODEL + nt + j];
  }
  __syncthreads();
#pragma unroll
  for (int ii = 0; ii < 4; ++ii) {
    int r = i + ii * 8;
    float v = ls[j][r];
    if (mat == 0) v *= QSCALE;
    unsigned short h = f2bf(v);
    size_t o = (size_t)(nt + r) * D_MODEL + kt + j;
    oh[o] = h;
    ol[o] = f2bf(v - bf2f(h));
  }
}

// ---------------- unified GEMM: C = A @ W^T(hi+lo) + bias, 4 epilogues ----------------
__global__ __launch_bounds__(256, 3) void gemm_kernel(
    const unsigned short* __restrict__ A0, const unsigned short* __restrict__ A1,
    const unsigned short* __restrict__ A2,
    const unsigned short* __restrict__ wth, const unsigned short* __restrict__ wtl,
    const float* __restrict__ b0, const float* __restrict__ b1,
    const float* __restrict__ b2, const float* __restrict__ b3,
    unsigned short* __restrict__ qh, unsigned short* __restrict__ kh,
    unsigned short* __restrict__ vt, float* __restrict__ o32, int zbase) {
  int z = zbase + blockIdx.z;
  const unsigned short* A = (z == 0) ? A0 : (z == 1) ? A1 : (z == 2) ? A2 : A0;
  const unsigned short* Bh = wth + ((size_t)z << 20);
  const unsigned short* Bl = wtl + ((size_t)z << 20);
  const float* bias = (z == 0) ? b0 : (z == 1) ? b1 : (z == 2) ? b2 : b3;
  float bsc = (z == 0) ? QSCALE : 1.0f;

  int bm = blockIdx.y, bn = blockIdx.x;
  int tid = threadIdx.x, lane = tid & 63, w = tid >> 6;
  int wr = w >> 1, wc = w & 1, l16 = lane & 15, l4 = lane >> 4;

  __shared__ unsigned short As[2][128 * 32];
  __shared__ unsigned short Bsh[2][128 * 32];
  __shared__ unsigned short Bsl[2][128 * 32];

  const unsigned short* Ab = A + (size_t)(bm * 128) * D_MODEL;
  const unsigned short* Bhb = Bh + (size_t)(bn * 128) * D_MODEL;
  const unsigned short* Blb = Bl + (size_t)(bn * 128) * D_MODEL;

  int r0 = tid >> 2, g0 = tid & 3;
  int r1 = (256 + tid) >> 2, g1 = tid & 3;
  int s0 = (r0 ^ (r0 >> 2)) & 3, s1 = (r1 ^ (r1 >> 2)) & 3;
  size_t so0 = (size_t)r0 * D_MODEL + ((g0 ^ s0) * 8);
  size_t so1 = (size_t)r1 * D_MODEL + ((g1 ^ s1) * 8);
  int ld0 = (w * 64) * 8;
  int ld1 = (256 + w * 64) * 8;

  int offA[4], offB[4];
#pragma unroll
  for (int m = 0; m < 4; ++m) {
    int row = wr * 64 + m * 16 + l16;
    int sw = (row ^ (row >> 2)) & 3;
    offA[m] = row * 32 + ((l4 ^ sw)) * 8;
  }
#pragma unroll
  for (int n = 0; n < 4; ++n) {
    int row = wc * 64 + n * 16 + l16;
    int sw = (row ^ (row >> 2)) & 3;
    offB[n] = row * 32 + ((l4 ^ sw)) * 8;
  }

  f4 acc[4][4];
  const f4 zf = {0.f, 0.f, 0.f, 0.f};
#pragma unroll
  for (int m = 0; m < 4; ++m)
#pragma unroll
    for (int n = 0; n < 4; ++n) acc[m][n] = zf;

  gl16(Ab + so0, &As[0][ld0]);  gl16(Ab + so1, &As[0][ld1]);
  gl16(Bhb + so0, &Bsh[0][ld0]); gl16(Bhb + so1, &Bsh[0][ld1]);
  gl16(Blb + so0, &Bsl[0][ld0]); gl16(Blb + so1, &Bsl[0][ld1]);
  __syncthreads();

  int cur = 0;
  for (int i = 0; i < 32; ++i) {
    if (i < 31) {
      int ktn = (i + 1) * 32;
      gl16(Ab + ktn + so0, &As[cur ^ 1][ld0]);  gl16(Ab + ktn + so1, &As[cur ^ 1][ld1]);
      gl16(Bhb + ktn + so0, &Bsh[cur ^ 1][ld0]); gl16(Bhb + ktn + so1, &Bsh[cur ^ 1][ld1]);
      gl16(Blb + ktn + so0, &Bsl[cur ^ 1][ld0]); gl16(Blb + ktn + so1, &Bsl[cur ^ 1][ld1]);
    }
    bf8 a[4], bh[4], bl[4];
#pragma unroll
    for (int m = 0; m < 4; ++m)
      a[m] = *reinterpret_cast<const bf8*>(&As[cur][offA[m]]);
#pragma unroll
    for (int n = 0; n < 4; ++n) {
      bh[n] = *reinterpret_cast<const bf8*>(&Bsh[cur][offB[n]]);
      bl[n] = *reinterpret_cast<const bf8*>(&Bsl[cur][offB[n]]);
    }
#pragma unroll
    for (int m = 0; m < 4; ++m)
#pragma unroll
      for (int n = 0; n < 4; ++n) {
        acc[m][n] = mfma16(a[m], bh[n], acc[m][n]);
        acc[m][n] = mfma16(a[m], bl[n], acc[m][n]);
      }
    __syncthreads();
    cur ^= 1;
  }

#pragma unroll
  for (int n = 0; n < 4; ++n) {
    int col = bn * 128 + wc * 64 + n * 16 + l16;
    float bb = bias[col] * bsc;
#pragma unroll
    for (int m = 0; m < 4; ++m) {
      int row0 = bm * 128 + wr * 64 + m * 16 + l4 * 4;
      if (z == 0) {
#pragma unroll
        for (int r = 0; r < 4; ++r)
          qh[(size_t)(row0 + r) * D_MODEL + col] = f2bf(acc[m][n][r] + bb);
      } else if (z == 1) {
#pragma unroll
        for (int r = 0; r < 4; ++r)
          kh[(size_t)(row0 + r) * D_MODEL + col] = f2bf(acc[m][n][r] + bb);
      } else if (z == 2) {
        int bb2 = row0 >> 11, ss = row0 & (SEQ - 1);
        int hh2 = col >> 6, dd = col & 63;
        union { us4 s; uint2 u; } pk4;
        pk4.u.x = pkbf(acc[m][n][0] + bb, acc[m][n][1] + bb);
        pk4.u.y = pkbf(acc[m][n][2] + bb, acc[m][n][3] + bb);
        *reinterpret_cast<us4*>(vt + ((size_t)(bb2 * NH + hh2) * HD + dd) * SEQ + ss) = pk4.s;
      } else {
#pragma unroll
        for (int r = 0; r < 4; ++r)
          o32[(size_t)(row0 + r) * D_MODEL + col] = acc[m][n][r] + bb;
      }
    }
  }
}

// ---------------- flash attention, swapped-operand + ZERO-SHUFFLE PV ----------------
// r4 geometry: 512 blocks (2/CU), 4 waves, wave owns 32 q-rows (m=0,1), full
// 64-key strip per wave, K/V^T double-buffered LDS via global_load_lds.
// Swapped QK^T (S^T = K*Q^T): lane owns q=l16 with keys c*16+l4*4+r in regs.
// That C-layout IS the low-half B-frag k-layout of mfma_16x16x32 -> PV uses
// zero-padded K=16 windows: P packs straight from cvt_pk into the MFMA
// B-operand. NO ds_bpermute, NO selects (r7-verified arithmetic).
__global__ __launch_bounds__(256) void attn_kernel(
    const unsigned short* __restrict__ qh, const unsigned short* __restrict__ kh,
    const unsigned short* __restrict__ vt, unsigned short* __restrict__ aout) {
  // XCD-aware bijective swizzle: 512 blocks, 8 XCDs -> 64 contiguous per XCD
  int orig = blockIdx.x + (blockIdx.y << 4) + (blockIdx.z << 8);
  int swz = ((orig & 7) << 6) + (orig >> 3);
  int qt = swz & 15, h = (swz >> 4) & 15, b = swz >> 8;

  int tid = threadIdx.x;
  int lane = tid & 63, w = tid >> 6;
  int l16 = lane & 15, l4 = lane >> 4;
  int l8r = lane >> 3, l8c = lane & 7;

  __shared__ unsigned short lds[16384];   // 2x4096 K + 2x4096 V^T; reused as trbuf

  const unsigned short* Kh = kh + (size_t)b * SEQ * D_MODEL + h * HD;
  const unsigned short* Vt = vt + (size_t)(b * NH + h) * HD * SEQ;

  // q B-frags: rows qt*128 + w*32 + m*16 + l16
  bf8 qf[2][2];
#pragma unroll
  for (int m = 0; m < 2; ++m) {
    size_t qo = (size_t)(b * SEQ + qt * 128 + w * 32 + m * 16 + l16) * D_MODEL + h * HD + l4 * 8;
    qf[m][0] = *reinterpret_cast<const bf8*>(qh + qo);
    qf[m][1] = *reinterpret_cast<const bf8*>(qh + qo + 32);
  }
  // ones A-frag (denominator MFMA; only low k-half matters vs zero-padded P)
  bf8 ones;
#pragma unroll
  for (int j = 0; j < 8; ++j) ones[j] = (short)0x3F80;

  const f4 zf = {0.f, 0.f, 0.f, 0.f};
  f4 acc[2][4];               // O^T per m: rows d=nt*16+l4*4+r, col q=l16
  f4 accs[2] = {zf, zf};      // denominators (all entries equal)
  float mr[2] = {0.f, 0.f};   // running max (defer-max)
#pragma unroll
  for (int m = 0; m < 2; ++m)
#pragma unroll
    for (int nt = 0; nt < 4; ++nt) acc[m][nt] = zf;

  const int sgr = (l8c ^ l8r) * 8;   // pre-swizzled source granule
  const int sl1 = w, sl2 = w + 4;    // wave's two 1KB staging slices

  // K A-frag read offsets (full d=64 per 16-key group c)
  const int swk = l16 & 7;
  // V read: window c, keys c*16 + l4*4 .. +3 at row d: granule gvc = 2c + (l4>>1)
  const int vsub = ((l4 & 1) << 2);

  // stage tile 0
  gl16(Kh + (size_t)(8 * sl1 + l8r) * D_MODEL + sgr, &lds[0 * 4096 + sl1 * 512]);
  gl16(Kh + (size_t)(8 * sl2 + l8r) * D_MODEL + sgr, &lds[0 * 4096 + sl2 * 512]);
  gl16(Vt + (size_t)(8 * sl1 + l8r) * SEQ + sgr, &lds[8192 + sl1 * 512]);
  gl16(Vt + (size_t)(8 * sl2 + l8r) * SEQ + sgr, &lds[8192 + sl2 * 512]);
  __syncthreads();

  int cur = 0;
  for (int kv = 0; kv < SEQ / 64; ++kv) {
    if (kv < SEQ / 64 - 1) {
      int k0n = (kv + 1) * 64;
      unsigned short* kd = &lds[(cur ^ 1) * 4096];
      unsigned short* vd2 = &lds[8192 + (cur ^ 1) * 4096];
      gl16(Kh + (size_t)(k0n + 8 * sl1 + l8r) * D_MODEL + sgr, kd + sl1 * 512);
      gl16(Kh + (size_t)(k0n + 8 * sl2 + l8r) * D_MODEL + sgr, kd + sl2 * 512);
      gl16(Vt + (size_t)(8 * sl1 + l8r) * SEQ + k0n + sgr, vd2 + sl1 * 512);
      gl16(Vt + (size_t)(8 * sl2 + l8r) * SEQ + k0n + sgr, vd2 + sl2 * 512);
    }
    const unsigned short* khb = &lds[cur * 4096];
    const unsigned short* vlb = &lds[8192 + cur * 4096];

    // K A-frags: A[row=key(tile-local), k=d]
    bf8 kb[4][2];
#pragma unroll
    for (int c = 0; c < 4; ++c) {
      int row = c * 16 + l16;
      kb[c][0] = *reinterpret_cast<const bf8*>(&khb[row * 64 + ((l4 ^ swk) * 8)]);
      kb[c][1] = *reinterpret_cast<const bf8*>(&khb[row * 64 + (((4 + l4) ^ swk) * 8)]);
    }
    // swapped QK^T: sc[m][c] = S^T rows key=c*16+l4*4+r, col q=l16
    f4 sc[2][4];
    __builtin_amdgcn_s_setprio(1);
#pragma unroll
    for (int m = 0; m < 2; ++m)
#pragma unroll
      for (int c = 0; c < 4; ++c) {
        f4 sv = zf;
        sv = mfma16(kb[c][0], qf[m][0], sv);
        sv = mfma16(kb[c][1], qf[m][1], sv);
        sc[m][c] = sv;
      }
    __builtin_amdgcn_s_setprio(0);
    // V chunks: window c, keys c*16+l4*4..+3, rows nt*16+l16 (uint2 each);
    // issued now so DS latency hides under softmax VALU
    uint2 vdr[4][4];
#pragma unroll
    for (int c = 0; c < 4; ++c) {
      int gvc = 2 * c + (l4 >> 1);
      int voff = ((gvc ^ swk) << 3) + vsub;
#pragma unroll
      for (int nt = 0; nt < 4; ++nt)
        vdr[c][nt] = *reinterpret_cast<const uint2*>(&vlb[(nt * 16 + l16) * 64 + voff]);
    }
    // softmax (base 2) per m: in-register, defer-max THR=8
    unsigned Wp[2][4][2];
#pragma unroll
    for (int m = 0; m < 2; ++m) {
      float tc0 = fmaxf(fmaxf(sc[m][0][0], sc[m][0][1]), fmaxf(sc[m][0][2], sc[m][0][3]));
      float tc1 = fmaxf(fmaxf(sc[m][1][0], sc[m][1][1]), fmaxf(sc[m][1][2], sc[m][1][3]));
      float tc2 = fmaxf(fmaxf(sc[m][2][0], sc[m][2][1]), fmaxf(sc[m][2][2], sc[m][2][3]));
      float tc3 = fmaxf(fmaxf(sc[m][3][0], sc[m][3][1]), fmaxf(sc[m][3][2], sc[m][3][3]));
      float tm = fmaxf(fmaxf(tc0, tc1), fmaxf(tc2, tc3));
      tm = fmaxf(tm, __shfl_xor(tm, 16));
      tm = fmaxf(tm, __shfl_xor(tm, 32));
      if (__any(tm > mr[m] + 8.0f)) {
        float mn = fmaxf(mr[m], tm);
        float al = ex2(mr[m] - mn);
        mr[m] = mn;
        accs[m][0] *= al; accs[m][1] *= al; accs[m][2] *= al; accs[m][3] *= al;
#pragma unroll
        for (int nt = 0; nt < 4; ++nt) {
          acc[m][nt][0] *= al; acc[m][nt][1] *= al;
          acc[m][nt][2] *= al; acc[m][nt][3] *= al;
        }
      }
#pragma unroll
      for (int c = 0; c < 4; ++c) {
        float p0 = ex2(sc[m][c][0] - mr[m]);
        float p1 = ex2(sc[m][c][1] - mr[m]);
        float p2 = ex2(sc[m][c][2] - mr[m]);
        float p3 = ex2(sc[m][c][3] - mr[m]);
        Wp[m][c][0] = pkbf(p0, p1);
        Wp[m][c][1] = pkbf(p2, p3);
      }
    }
    // PV + denominator: zero-padded K=16 windows, no cross-lane movement
    __builtin_amdgcn_s_setprio(1);
#pragma unroll
    for (int c = 0; c < 4; ++c)
#pragma unroll
      for (int m = 0; m < 2; ++m) {
        union { bf8 v; unsigned u[4]; } pu;
        pu.u[0] = Wp[m][c][0]; pu.u[1] = Wp[m][c][1]; pu.u[2] = 0; pu.u[3] = 0;
        accs[m] = mfma16(ones, pu.v, accs[m]);
#pragma unroll
        for (int nt = 0; nt < 4; ++nt) {
          union { bf8 v; unsigned u[4]; } vu;
          vu.u[0] = vdr[c][nt].x; vu.u[1] = vdr[c][nt].y; vu.u[2] = 0; vu.u[3] = 0;
          acc[m][nt] = mfma16(vu.v, pu.v, acc[m][nt]);
        }
      }
    __builtin_amdgcn_s_setprio(0);
    __syncthreads();
    cur ^= 1;
  }

  // epilogue: normalize, transpose O^T -> O via freed LDS
  float inv[2];
#pragma unroll
  for (int m = 0; m < 2; ++m) inv[m] = 1.0f / accs[m][0];
#pragma unroll
  for (int m = 0; m < 2; ++m) {
    int q = w * 32 + m * 16 + l16;
    int sw = (q & 7) << 3;
#pragma unroll
    for (int nt = 0; nt < 4; ++nt) {
      uint2 pw;
      pw.x = pkbf(acc[m][nt][0] * inv[m], acc[m][nt][1] * inv[m]);
      pw.y = pkbf(acc[m][nt][2] * inv[m], acc[m][nt][3] * inv[m]);
      int d0 = nt * 16 + l4 * 4;
      *reinterpret_cast<uint2*>(&lds[q * 64 + (d0 ^ sw)]) = pw;
    }
  }
  __syncthreads();
  {
    int q = tid >> 1, dh = (tid & 1) * 32, sw = (q & 7) << 3;
    size_t orow = ((size_t)(b * SEQ + qt * 128 + q)) * D_MODEL + h * HD + dh;
#pragma unroll
    for (int j = 0; j < 4; ++j) {
      us8 vv = *reinterpret_cast<const us8*>(&lds[q * 64 + ((dh + j * 8) ^ sw)]);
      *reinterpret_cast<us8*>(&aout[orow + j * 8]) = vv;
    }
  }
}

extern "C" void kernel_launch(void* const* d_in, const int* in_sizes, int n_in,
                              void* d_out, int out_size, void* d_ws, size_t ws_size,
                              hipStream_t stream) {
  const float* Q  = (const float*)d_in[0];
  const float* K  = (const float*)d_in[1];
  const float* V  = (const float*)d_in[2];
  const float* Wq = (const float*)d_in[3];
  const float* bq = (const float*)d_in[4];
  const float* Wk = (const float*)d_in[5];
  const float* bk = (const float*)d_in[6];
  const float* Wv = (const float*)d_in[7];
  const float* bv = (const float*)d_in[8];
  const float* Wo = (const float*)d_in[9];
  const float* bo = (const float*)d_in[10];
  float* out = (float*)d_out;

  // workspace (56 MB) + d_out doubles as Q/K bf16 scratch (overwritten by final GEMM)
  unsigned char* ws = (unsigned char*)d_ws;
  const size_t MB = 1024 * 1024;
  unsigned short* wthi = (unsigned short*)(ws);             // 4x W^T hi      (8 MB)
  unsigned short* wtlo = (unsigned short*)(ws + 8 * MB);    // 4x W^T lo      (8 MB)
  unsigned short* qh   = (unsigned short*)(ws + 16 * MB);   // q bf16 [B,S,D] (8 MB)
  unsigned short* kh   = (unsigned short*)(ws + 24 * MB);   // k bf16         (8 MB)
  unsigned short* vt   = (unsigned short*)(ws + 32 * MB);   // V^T [B,H,d,S]  (8 MB)
  unsigned short* ah   = (unsigned short*)(ws + 40 * MB);   // attn out bf16  (8 MB)
  unsigned short* vbf  = (unsigned short*)(ws + 48 * MB);   // V input bf16   (8 MB)
  unsigned short* qbf  = (unsigned short*)d_out;            // Q input bf16 (scratch)
  unsigned short* kbf  = (unsigned short*)d_out + 4 * MB;   // K input bf16 (scratch)

  convert_inputs<<<dim3(2048, 1, 3), 256, 0, stream>>>(Q, K, V, qbf, kbf, vbf);
  prep_weights<<<dim3(32, 32, 4), 256, 0, stream>>>(Wq, Wk, Wv, Wo, wthi, wtlo);
  gemm_kernel<<<dim3(8, 32, 3), 256, 0, stream>>>(qbf, kbf, vbf, wthi, wtlo,
                                                  bq, bk, bv, bo, qh, kh, vt, out, 0);
  attn_kernel<<<dim3(16, NH, NB), 256, 0, stream>>>(qh, kh, vt, ah);
  gemm_kernel<<<dim3(8, 32, 1), 256, 0, stream>>>(ah, ah, ah, wthi, wtlo,
                                                  bq, bk, bv, bo, qh, kh, vt, out, 3);
}

// Round 9
// 150.552 us; speedup vs baseline: 1.5376x; 1.2285x over previous
//
#include <hip/hip_runtime.h>
#include <cstdint>
#include <cstddef>

#define D_MODEL 1024
#define HD 64
#define NH 16
#define SEQ 2048
#define NB 2

typedef __attribute__((ext_vector_type(8))) short bf8;           // 8 bf16 (4 VGPR)
typedef __attribute__((ext_vector_type(8))) unsigned short us8;
typedef __attribute__((ext_vector_type(4))) unsigned short us4;
typedef __attribute__((ext_vector_type(4))) float f4;

__device__ __forceinline__ float bf2f(unsigned short u) {
  union { unsigned int i; float f; } c; c.i = ((unsigned int)u) << 16; return c.f;
}
__device__ __forceinline__ unsigned short f2bf(float x) {
  union { float f; unsigned int i; } c; c.f = x;
  unsigned int r = (c.i + 0x7FFFu + ((c.i >> 16) & 1u)) >> 16;   // RNE
  return (unsigned short)r;
}
// packed f32x2 -> bf16x2 (RNE), single HW op
__device__ __forceinline__ unsigned int pkbf(float lo, float hi) {
  unsigned int r;
  asm("v_cvt_pk_bf16_f32 %0, %1, %2" : "=v"(r) : "v"(lo), "v"(hi));
  return r;
}
// exp2 via v_exp_f32 (D = 2^S0)
__device__ __forceinline__ float ex2(float x) {
  float r;
  asm("v_exp_f32 %0, %1" : "=v"(r) : "v"(x));
  return r;
}
__device__ __forceinline__ f4 mfma16(bf8 a, bf8 b, f4 c) {
  return __builtin_amdgcn_mfma_f32_16x16x32_bf16(a, b, c, 0, 0, 0);
}
// async global->LDS, 16B per lane; LDS dest = wave-uniform base + lane*16
__device__ __forceinline__ void gl16(const unsigned short* g, unsigned short* l) {
  __builtin_amdgcn_global_load_lds(
      (const __attribute__((address_space(1))) unsigned int*)g,
      (__attribute__((address_space(3))) unsigned int*)l, 16, 0, 0);
}

#define QSCALE (0.125f * 1.44269504088896f)   // 1/sqrt(64) * log2(e)

// ---------------- fused prep: input bf16 convert + weight transpose/split ----------------
// 1D grid, 10240 blocks: [0,6144) convert Q/K/V fp32->bf16; [6144,10240) weights.
// Weights: W^T hi for all 4 mats; lo only for mat 3 (Wo; only fp32-output GEMM
// benefits -- q/k/v outputs are bf16-rounded anyway, r3-verified no-op).
__global__ __launch_bounds__(256) void prep_all(
    const float* __restrict__ Q, const float* __restrict__ K, const float* __restrict__ V,
    const float* __restrict__ Wq, const float* __restrict__ Wk,
    const float* __restrict__ Wv, const float* __restrict__ Wo,
    unsigned short* __restrict__ dq, unsigned short* __restrict__ dk,
    unsigned short* __restrict__ dv,
    unsigned short* __restrict__ wthi, unsigned short* __restrict__ wtlo) {
  int bid = blockIdx.x;
  __shared__ float ls[32][33];
  if (bid < 6144) {
    int z = bid >> 11, x = bid & 2047;
    const float* s = (z == 0) ? Q : (z == 1) ? K : V;
    unsigned short* d = (z == 0) ? dq : (z == 1) ? dk : dv;
    size_t i = ((size_t)x * 256 + threadIdx.x) * 8;
    float4 a = *reinterpret_cast<const float4*>(s + i);
    float4 b = *reinterpret_cast<const float4*>(s + i + 4);
    union { us8 v; unsigned int u[4]; } o;
    o.u[0] = pkbf(a.x, a.y); o.u[1] = pkbf(a.z, a.w);
    o.u[2] = pkbf(b.x, b.y); o.u[3] = pkbf(b.z, b.w);
    *reinterpret_cast<us8*>(d + i) = o.v;
  } else {
    int j = bid - 6144;
    int mat = j >> 10, rem = j & 1023;
    int kt = (rem >> 5) * 32, nt = (rem & 31) * 32;
    const float* W = (mat == 0) ? Wq : (mat == 1) ? Wk : (mat == 2) ? Wv : Wo;
    unsigned short* oh = wthi + ((size_t)mat << 20);
    unsigned short* ol = wtlo + ((size_t)mat << 20);
    int i = threadIdx.x >> 5;
    int jj = threadIdx.x & 31;
#pragma unroll
    for (int ii = 0; ii < 4; ++ii) {
      int r = i + ii * 8;
      ls[r][jj] = W[(size_t)(kt + r) * D_MODEL + nt + jj];
    }
    __syncthreads();
#pragma unroll
    for (int ii = 0; ii < 4; ++ii) {
      int r = i + ii * 8;
      float v = ls[jj][r];
      if (mat == 0) v *= QSCALE;
      unsigned short h = f2bf(v);
      size_t o = (size_t)(nt + r) * D_MODEL + kt + jj;
      oh[o] = h;
      if (mat == 3) ol[o] = f2bf(v - bf2f(h));
    }
  }
}

// ---------------- proj GEMM (hi-only): C = A @ W^T + bias, 3 epilogues ----------------
// z=0: q->qh, z=1: k->kh, z=2: v->vt (transposed). 128x128 tile, BK=32,
// 4 waves 2x2, A/Bh staged via global_load_lds, double-buffered, XOR granules.
__global__ __launch_bounds__(256, 3) void gemm_kernel(
    const unsigned short* __restrict__ A0, const unsigned short* __restrict__ A1,
    const unsigned short* __restrict__ A2, const unsigned short* __restrict__ wth,
    const float* __restrict__ b0, const float* __restrict__ b1,
    const float* __restrict__ b2,
    unsigned short* __restrict__ qh, unsigned short* __restrict__ kh,
    unsigned short* __restrict__ vt) {
  int z = blockIdx.z;
  const unsigned short* A = (z == 0) ? A0 : (z == 1) ? A1 : A2;
  const unsigned short* Bh = wth + ((size_t)z << 20);
  const float* bias = (z == 0) ? b0 : (z == 1) ? b1 : b2;
  float bsc = (z == 0) ? QSCALE : 1.0f;

  int bm = blockIdx.y, bn = blockIdx.x;
  int tid = threadIdx.x, lane = tid & 63, w = tid >> 6;
  int wr = w >> 1, wc = w & 1, l16 = lane & 15, l4 = lane >> 4;

  __shared__ unsigned short As[2][128 * 32];
  __shared__ unsigned short Bsh[2][128 * 32];

  const unsigned short* Ab = A + (size_t)(bm * 128) * D_MODEL;
  const unsigned short* Bhb = Bh + (size_t)(bn * 128) * D_MODEL;

  int r0 = tid >> 2, g0 = tid & 3;
  int r1 = (256 + tid) >> 2, g1 = tid & 3;
  int s0 = (r0 ^ (r0 >> 2)) & 3, s1 = (r1 ^ (r1 >> 2)) & 3;
  size_t so0 = (size_t)r0 * D_MODEL + ((g0 ^ s0) * 8);
  size_t so1 = (size_t)r1 * D_MODEL + ((g1 ^ s1) * 8);
  int ld0 = (w * 64) * 8;
  int ld1 = (256 + w * 64) * 8;

  int offA[4], offB[4];
#pragma unroll
  for (int m = 0; m < 4; ++m) {
    int row = wr * 64 + m * 16 + l16;
    int sw = (row ^ (row >> 2)) & 3;
    offA[m] = row * 32 + ((l4 ^ sw)) * 8;
  }
#pragma unroll
  for (int n = 0; n < 4; ++n) {
    int row = wc * 64 + n * 16 + l16;
    int sw = (row ^ (row >> 2)) & 3;
    offB[n] = row * 32 + ((l4 ^ sw)) * 8;
  }

  f4 acc[4][4];
  const f4 zf = {0.f, 0.f, 0.f, 0.f};
#pragma unroll
  for (int m = 0; m < 4; ++m)
#pragma unroll
    for (int n = 0; n < 4; ++n) acc[m][n] = zf;

  gl16(Ab + so0, &As[0][ld0]);  gl16(Ab + so1, &As[0][ld1]);
  gl16(Bhb + so0, &Bsh[0][ld0]); gl16(Bhb + so1, &Bsh[0][ld1]);
  __syncthreads();

  int cur = 0;
  for (int i = 0; i < 32; ++i) {
    if (i < 31) {
      int ktn = (i + 1) * 32;
      gl16(Ab + ktn + so0, &As[cur ^ 1][ld0]);  gl16(Ab + ktn + so1, &As[cur ^ 1][ld1]);
      gl16(Bhb + ktn + so0, &Bsh[cur ^ 1][ld0]); gl16(Bhb + ktn + so1, &Bsh[cur ^ 1][ld1]);
    }
    bf8 a[4], bh[4];
#pragma unroll
    for (int m = 0; m < 4; ++m)
      a[m] = *reinterpret_cast<const bf8*>(&As[cur][offA[m]]);
#pragma unroll
    for (int n = 0; n < 4; ++n)
      bh[n] = *reinterpret_cast<const bf8*>(&Bsh[cur][offB[n]]);
#pragma unroll
    for (int m = 0; m < 4; ++m)
#pragma unroll
      for (int n = 0; n < 4; ++n)
        acc[m][n] = mfma16(a[m], bh[n], acc[m][n]);
    __syncthreads();
    cur ^= 1;
  }

#pragma unroll
  for (int n = 0; n < 4; ++n) {
    int col = bn * 128 + wc * 64 + n * 16 + l16;
    float bb = bias[col] * bsc;
#pragma unroll
    for (int m = 0; m < 4; ++m) {
      int row0 = bm * 128 + wr * 64 + m * 16 + l4 * 4;
      if (z == 0) {
#pragma unroll
        for (int r = 0; r < 4; ++r)
          qh[(size_t)(row0 + r) * D_MODEL + col] = f2bf(acc[m][n][r] + bb);
      } else if (z == 1) {
#pragma unroll
        for (int r = 0; r < 4; ++r)
          kh[(size_t)(row0 + r) * D_MODEL + col] = f2bf(acc[m][n][r] + bb);
      } else {
        int bb2 = row0 >> 11, ss = row0 & (SEQ - 1);
        int hh2 = col >> 6, dd = col & 63;
        union { us4 s; uint2 u; } pk4;
        pk4.u.x = pkbf(acc[m][n][0] + bb, acc[m][n][1] + bb);
        pk4.u.y = pkbf(acc[m][n][2] + bb, acc[m][n][3] + bb);
        *reinterpret_cast<us4*>(vt + ((size_t)(bb2 * NH + hh2) * HD + dd) * SEQ + ss) = pk4.s;
      }
    }
  }
}

// ---------------- out GEMM (hi+lo, fp32 out): 128x64 tile, grid (16,32)=512 ----------------
__global__ __launch_bounds__(256, 3) void out_gemm(
    const unsigned short* __restrict__ ah, const unsigned short* __restrict__ wth,
    const unsigned short* __restrict__ wtl, const float* __restrict__ bo,
    float* __restrict__ o32) {
  const unsigned short* Bh = wth + ((size_t)3 << 20);
  const unsigned short* Bl = wtl + ((size_t)3 << 20);
  int bm = blockIdx.y, bn = blockIdx.x;
  int tid = threadIdx.x, lane = tid & 63, w = tid >> 6;
  int wr = w >> 1, wc = w & 1, l16 = lane & 15, l4 = lane >> 4;

  __shared__ unsigned short As[2][128 * 32];
  __shared__ unsigned short Bsh[2][64 * 32];
  __shared__ unsigned short Bsl[2][64 * 32];

  const unsigned short* Ab = ah + (size_t)(bm * 128) * D_MODEL;
  const unsigned short* Bhb = Bh + (size_t)(bn * 64) * D_MODEL;
  const unsigned short* Blb = Bl + (size_t)(bn * 64) * D_MODEL;

  int r0 = tid >> 2, g0 = tid & 3;
  int r1 = (256 + tid) >> 2;
  int s0 = (r0 ^ (r0 >> 2)) & 3, s1 = (r1 ^ (r1 >> 2)) & 3;
  size_t so0 = (size_t)r0 * D_MODEL + ((g0 ^ s0) * 8);   // rows 0..63 (also B round)
  size_t so1 = (size_t)r1 * D_MODEL + ((g0 ^ s1) * 8);   // rows 64..127 (A only)
  int ld0 = (w * 64) * 8;
  int ld1 = (256 + w * 64) * 8;

  int offA[4], offB[2];
#pragma unroll
  for (int m = 0; m < 4; ++m) {
    int row = wr * 64 + m * 16 + l16;
    int sw = (row ^ (row >> 2)) & 3;
    offA[m] = row * 32 + ((l4 ^ sw)) * 8;
  }
#pragma unroll
  for (int n = 0; n < 2; ++n) {
    int row = wc * 32 + n * 16 + l16;
    int sw = (row ^ (row >> 2)) & 3;
    offB[n] = row * 32 + ((l4 ^ sw)) * 8;
  }

  f4 acc[4][2];
  const f4 zf = {0.f, 0.f, 0.f, 0.f};
#pragma unroll
  for (int m = 0; m < 4; ++m)
#pragma unroll
    for (int n = 0; n < 2; ++n) acc[m][n] = zf;

  gl16(Ab + so0, &As[0][ld0]); gl16(Ab + so1, &As[0][ld1]);
  gl16(Bhb + so0, &Bsh[0][ld0]);
  gl16(Blb + so0, &Bsl[0][ld0]);
  __syncthreads();

  int cur = 0;
  for (int i = 0; i < 32; ++i) {
    if (i < 31) {
      int ktn = (i + 1) * 32;
      gl16(Ab + ktn + so0, &As[cur ^ 1][ld0]); gl16(Ab + ktn + so1, &As[cur ^ 1][ld1]);
      gl16(Bhb + ktn + so0, &Bsh[cur ^ 1][ld0]);
      gl16(Blb + ktn + so0, &Bsl[cur ^ 1][ld0]);
    }
    bf8 a[4], bh[2], bl[2];
#pragma unroll
    for (int m = 0; m < 4; ++m)
      a[m] = *reinterpret_cast<const bf8*>(&As[cur][offA[m]]);
#pragma unroll
    for (int n = 0; n < 2; ++n) {
      bh[n] = *reinterpret_cast<const bf8*>(&Bsh[cur][offB[n]]);
      bl[n] = *reinterpret_cast<const bf8*>(&Bsl[cur][offB[n]]);
    }
#pragma unroll
    for (int m = 0; m < 4; ++m)
#pragma unroll
      for (int n = 0; n < 2; ++n) {
        acc[m][n] = mfma16(a[m], bh[n], acc[m][n]);
        acc[m][n] = mfma16(a[m], bl[n], acc[m][n]);
      }
    __syncthreads();
    cur ^= 1;
  }

#pragma unroll
  for (int n = 0; n < 2; ++n) {
    int col = bn * 64 + wc * 32 + n * 16 + l16;
    float bb = bo[col];
#pragma unroll
    for (int m = 0; m < 4; ++m) {
      int row0 = bm * 128 + wr * 64 + m * 16 + l4 * 4;
#pragma unroll
      for (int r = 0; r < 4; ++r)
        o32[(size_t)(row0 + r) * D_MODEL + col] = acc[m][n][r] + bb;
    }
  }
}

// ---------------- flash attention, swapped-operand + zero-shuffle PV (r8) ----------------
__global__ __launch_bounds__(256) void attn_kernel(
    const unsigned short* __restrict__ qh, const unsigned short* __restrict__ kh,
    const unsigned short* __restrict__ vt, unsigned short* __restrict__ aout) {
  // XCD-aware bijective swizzle: 512 blocks, 8 XCDs -> 64 contiguous per XCD
  int orig = blockIdx.x + (blockIdx.y << 4) + (blockIdx.z << 8);
  int swz = ((orig & 7) << 6) + (orig >> 3);
  int qt = swz & 15, h = (swz >> 4) & 15, b = swz >> 8;

  int tid = threadIdx.x;
  int lane = tid & 63, w = tid >> 6;
  int l16 = lane & 15, l4 = lane >> 4;
  int l8r = lane >> 3, l8c = lane & 7;

  __shared__ unsigned short lds[16384];   // 2x4096 K + 2x4096 V^T; reused as trbuf

  const unsigned short* Kh = kh + (size_t)b * SEQ * D_MODEL + h * HD;
  const unsigned short* Vt = vt + (size_t)(b * NH + h) * HD * SEQ;

  // q B-frags: rows qt*128 + w*32 + m*16 + l16
  bf8 qf[2][2];
#pragma unroll
  for (int m = 0; m < 2; ++m) {
    size_t qo = (size_t)(b * SEQ + qt * 128 + w * 32 + m * 16 + l16) * D_MODEL + h * HD + l4 * 8;
    qf[m][0] = *reinterpret_cast<const bf8*>(qh + qo);
    qf[m][1] = *reinterpret_cast<const bf8*>(qh + qo + 32);
  }
  bf8 ones;
#pragma unroll
  for (int j = 0; j < 8; ++j) ones[j] = (short)0x3F80;

  const f4 zf = {0.f, 0.f, 0.f, 0.f};
  f4 acc[2][4];
  f4 accs[2] = {zf, zf};
  float mr[2] = {0.f, 0.f};
#pragma unroll
  for (int m = 0; m < 2; ++m)
#pragma unroll
    for (int nt = 0; nt < 4; ++nt) acc[m][nt] = zf;

  const int sgr = (l8c ^ l8r) * 8;
  const int sl1 = w, sl2 = w + 4;
  const int swk = l16 & 7;
  const int vsub = ((l4 & 1) << 2);

  gl16(Kh + (size_t)(8 * sl1 + l8r) * D_MODEL + sgr, &lds[0 * 4096 + sl1 * 512]);
  gl16(Kh + (size_t)(8 * sl2 + l8r) * D_MODEL + sgr, &lds[0 * 4096 + sl2 * 512]);
  gl16(Vt + (size_t)(8 * sl1 + l8r) * SEQ + sgr, &lds[8192 + sl1 * 512]);
  gl16(Vt + (size_t)(8 * sl2 + l8r) * SEQ + sgr, &lds[8192 + sl2 * 512]);
  __syncthreads();

  int cur = 0;
  for (int kv = 0; kv < SEQ / 64; ++kv) {
    if (kv < SEQ / 64 - 1) {
      int k0n = (kv + 1) * 64;
      unsigned short* kd = &lds[(cur ^ 1) * 4096];
      unsigned short* vd2 = &lds[8192 + (cur ^ 1) * 4096];
      gl16(Kh + (size_t)(k0n + 8 * sl1 + l8r) * D_MODEL + sgr, kd + sl1 * 512);
      gl16(Kh + (size_t)(k0n + 8 * sl2 + l8r) * D_MODEL + sgr, kd + sl2 * 512);
      gl16(Vt + (size_t)(8 * sl1 + l8r) * SEQ + k0n + sgr, vd2 + sl1 * 512);
      gl16(Vt + (size_t)(8 * sl2 + l8r) * SEQ + k0n + sgr, vd2 + sl2 * 512);
    }
    const unsigned short* khb = &lds[cur * 4096];
    const unsigned short* vlb = &lds[8192 + cur * 4096];

    bf8 kb[4][2];
#pragma unroll
    for (int c = 0; c < 4; ++c) {
      int row = c * 16 + l16;
      kb[c][0] = *reinterpret_cast<const bf8*>(&khb[row * 64 + ((l4 ^ swk) * 8)]);
      kb[c][1] = *reinterpret_cast<const bf8*>(&khb[row * 64 + (((4 + l4) ^ swk) * 8)]);
    }
    f4 sc[2][4];
    __builtin_amdgcn_s_setprio(1);
#pragma unroll
    for (int m = 0; m < 2; ++m)
#pragma unroll
      for (int c = 0; c < 4; ++c) {
        f4 sv = zf;
        sv = mfma16(kb[c][0], qf[m][0], sv);
        sv = mfma16(kb[c][1], qf[m][1], sv);
        sc[m][c] = sv;
      }
    __builtin_amdgcn_s_setprio(0);
    uint2 vdr[4][4];
#pragma unroll
    for (int c = 0; c < 4; ++c) {
      int gvc = 2 * c + (l4 >> 1);
      int voff = ((gvc ^ swk) << 3) + vsub;
#pragma unroll
      for (int nt = 0; nt < 4; ++nt)
        vdr[c][nt] = *reinterpret_cast<const uint2*>(&vlb[(nt * 16 + l16) * 64 + voff]);
    }
    unsigned Wp[2][4][2];
#pragma unroll
    for (int m = 0; m < 2; ++m) {
      float tc0 = fmaxf(fmaxf(sc[m][0][0], sc[m][0][1]), fmaxf(sc[m][0][2], sc[m][0][3]));
      float tc1 = fmaxf(fmaxf(sc[m][1][0], sc[m][1][1]), fmaxf(sc[m][1][2], sc[m][1][3]));
      float tc2 = fmaxf(fmaxf(sc[m][2][0], sc[m][2][1]), fmaxf(sc[m][2][2], sc[m][2][3]));
      float tc3 = fmaxf(fmaxf(sc[m][3][0], sc[m][3][1]), fmaxf(sc[m][3][2], sc[m][3][3]));
      float tm = fmaxf(fmaxf(tc0, tc1), fmaxf(tc2, tc3));
      tm = fmaxf(tm, __shfl_xor(tm, 16));
      tm = fmaxf(tm, __shfl_xor(tm, 32));
      if (__any(tm > mr[m] + 8.0f)) {
        float mn = fmaxf(mr[m], tm);
        float al = ex2(mr[m] - mn);
        mr[m] = mn;
        accs[m][0] *= al; accs[m][1] *= al; accs[m][2] *= al; accs[m][3] *= al;
#pragma unroll
        for (int nt = 0; nt < 4; ++nt) {
          acc[m][nt][0] *= al; acc[m][nt][1] *= al;
          acc[m][nt][2] *= al; acc[m][nt][3] *= al;
        }
      }
#pragma unroll
      for (int c = 0; c < 4; ++c) {
        float p0 = ex2(sc[m][c][0] - mr[m]);
        float p1 = ex2(sc[m][c][1] - mr[m]);
        float p2 = ex2(sc[m][c][2] - mr[m]);
        float p3 = ex2(sc[m][c][3] - mr[m]);
        Wp[m][c][0] = pkbf(p0, p1);
        Wp[m][c][1] = pkbf(p2, p3);
      }
    }
    __builtin_amdgcn_s_setprio(1);
#pragma unroll
    for (int c = 0; c < 4; ++c)
#pragma unroll
      for (int m = 0; m < 2; ++m) {
        union { bf8 v; unsigned u[4]; } pu;
        pu.u[0] = Wp[m][c][0]; pu.u[1] = Wp[m][c][1]; pu.u[2] = 0; pu.u[3] = 0;
        accs[m] = mfma16(ones, pu.v, accs[m]);
#pragma unroll
        for (int nt = 0; nt < 4; ++nt) {
          union { bf8 v; unsigned u[4]; } vu;
          vu.u[0] = vdr[c][nt].x; vu.u[1] = vdr[c][nt].y; vu.u[2] = 0; vu.u[3] = 0;
          acc[m][nt] = mfma16(vu.v, pu.v, acc[m][nt]);
        }
      }
    __builtin_amdgcn_s_setprio(0);
    __syncthreads();
    cur ^= 1;
  }

  float inv[2];
#pragma unroll
  for (int m = 0; m < 2; ++m) inv[m] = 1.0f / accs[m][0];
#pragma unroll
  for (int m = 0; m < 2; ++m) {
    int q = w * 32 + m * 16 + l16;
    int sw = (q & 7) << 3;
#pragma unroll
    for (int nt = 0; nt < 4; ++nt) {
      uint2 pw;
      pw.x = pkbf(acc[m][nt][0] * inv[m], acc[m][nt][1] * inv[m]);
      pw.y = pkbf(acc[m][nt][2] * inv[m], acc[m][nt][3] * inv[m]);
      int d0 = nt * 16 + l4 * 4;
      *reinterpret_cast<uint2*>(&lds[q * 64 + (d0 ^ sw)]) = pw;
    }
  }
  __syncthreads();
  {
    int q = tid >> 1, dh = (tid & 1) * 32, sw = (q & 7) << 3;
    size_t orow = ((size_t)(b * SEQ + qt * 128 + q)) * D_MODEL + h * HD + dh;
#pragma unroll
    for (int j = 0; j < 4; ++j) {
      us8 vv = *reinterpret_cast<const us8*>(&lds[q * 64 + ((dh + j * 8) ^ sw)]);
      *reinterpret_cast<us8*>(&aout[orow + j * 8]) = vv;
    }
  }
}

extern "C" void kernel_launch(void* const* d_in, const int* in_sizes, int n_in,
                              void* d_out, int out_size, void* d_ws, size_t ws_size,
                              hipStream_t stream) {
  const float* Q  = (const float*)d_in[0];
  const float* K  = (const float*)d_in[1];
  const float* V  = (const float*)d_in[2];
  const float* Wq = (const float*)d_in[3];
  const float* bq = (const float*)d_in[4];
  const float* Wk = (const float*)d_in[5];
  const float* bk = (const float*)d_in[6];
  const float* Wv = (const float*)d_in[7];
  const float* bv = (const float*)d_in[8];
  const float* Wo = (const float*)d_in[9];
  const float* bo = (const float*)d_in[10];
  float* out = (float*)d_out;

  // workspace (56 MB) + d_out doubles as Q/K bf16 scratch (overwritten by out_gemm)
  unsigned char* ws = (unsigned char*)d_ws;
  const size_t MB = 1024 * 1024;
  unsigned short* wthi = (unsigned short*)(ws);             // 4x W^T hi      (8 MB)
  unsigned short* wtlo = (unsigned short*)(ws + 8 * MB);    // W^T lo (mat 3) (8 MB)
  unsigned short* qh   = (unsigned short*)(ws + 16 * MB);   // q bf16 [B,S,D] (8 MB)
  unsigned short* kh   = (unsigned short*)(ws + 24 * MB);   // k bf16         (8 MB)
  unsigned short* vt   = (unsigned short*)(ws + 32 * MB);   // V^T [B,H,d,S]  (8 MB)
  unsigned short* ah   = (unsigned short*)(ws + 40 * MB);   // attn out bf16  (8 MB)
  unsigned short* vbf  = (unsigned short*)(ws + 48 * MB);   // V input bf16   (8 MB)
  unsigned short* qbf  = (unsigned short*)d_out;            // Q input bf16 (scratch)
  unsigned short* kbf  = (unsigned short*)d_out + 4 * MB;   // K input bf16 (scratch)

  prep_all<<<dim3(10240, 1, 1), 256, 0, stream>>>(Q, K, V, Wq, Wk, Wv, Wo,
                                                  qbf, kbf, vbf, wthi, wtlo);
  gemm_kernel<<<dim3(8, 32, 3), 256, 0, stream>>>(qbf, kbf, vbf, wthi,
                                                  bq, bk, bv, qh, kh, vt);
  attn_kernel<<<dim3(16, NH, NB), 256, 0, stream>>>(qh, kh, vt, ah);
  out_gemm<<<dim3(16, 32, 1), 256, 0, stream>>>(ah, wthi, wtlo, bo, out);
}

// Round 10
// 150.210 us; speedup vs baseline: 1.5411x; 1.0023x over previous
//
#include <hip/hip_runtime.h>
#include <cstdint>
#include <cstddef>

#define D_MODEL 1024
#define HD 64
#define NH 16
#define SEQ 2048
#define NB 2

typedef __attribute__((ext_vector_type(8))) short bf8;           // 8 bf16 (4 VGPR)
typedef __attribute__((ext_vector_type(8))) unsigned short us8;
typedef __attribute__((ext_vector_type(4))) unsigned short us4;
typedef __attribute__((ext_vector_type(4))) float f4;

__device__ __forceinline__ float bf2f(unsigned short u) {
  union { unsigned int i; float f; } c; c.i = ((unsigned int)u) << 16; return c.f;
}
__device__ __forceinline__ unsigned short f2bf(float x) {
  union { float f; unsigned int i; } c; c.f = x;
  unsigned int r = (c.i + 0x7FFFu + ((c.i >> 16) & 1u)) >> 16;   // RNE
  return (unsigned short)r;
}
// packed f32x2 -> bf16x2 (RNE), single HW op
__device__ __forceinline__ unsigned int pkbf(float lo, float hi) {
  unsigned int r;
  asm("v_cvt_pk_bf16_f32 %0, %1, %2" : "=v"(r) : "v"(lo), "v"(hi));
  return r;
}
// exp2 via v_exp_f32 (D = 2^S0)
__device__ __forceinline__ float ex2(float x) {
  float r;
  asm("v_exp_f32 %0, %1" : "=v"(r) : "v"(x));
  return r;
}
__device__ __forceinline__ f4 mfma16(bf8 a, bf8 b, f4 c) {
  return __builtin_amdgcn_mfma_f32_16x16x32_bf16(a, b, c, 0, 0, 0);
}
// async global->LDS, 16B per lane; LDS dest = wave-uniform base + lane*16
__device__ __forceinline__ void gl16(const unsigned short* g, unsigned short* l) {
  __builtin_amdgcn_global_load_lds(
      (const __attribute__((address_space(1))) unsigned int*)g,
      (__attribute__((address_space(3))) unsigned int*)l, 16, 0, 0);
}

#define QSCALE (0.125f * 1.44269504088896f)   // 1/sqrt(64) * log2(e)

// ---------------- fused prep: input bf16 convert + weight transpose/split ----------------
__global__ __launch_bounds__(256) void prep_all(
    const float* __restrict__ Q, const float* __restrict__ K, const float* __restrict__ V,
    const float* __restrict__ Wq, const float* __restrict__ Wk,
    const float* __restrict__ Wv, const float* __restrict__ Wo,
    unsigned short* __restrict__ dq, unsigned short* __restrict__ dk,
    unsigned short* __restrict__ dv,
    unsigned short* __restrict__ wthi, unsigned short* __restrict__ wtlo) {
  int bid = blockIdx.x;
  __shared__ float ls[32][33];
  if (bid < 6144) {
    int z = bid >> 11, x = bid & 2047;
    const float* s = (z == 0) ? Q : (z == 1) ? K : V;
    unsigned short* d = (z == 0) ? dq : (z == 1) ? dk : dv;
    size_t i = ((size_t)x * 256 + threadIdx.x) * 8;
    float4 a = *reinterpret_cast<const float4*>(s + i);
    float4 b = *reinterpret_cast<const float4*>(s + i + 4);
    union { us8 v; unsigned int u[4]; } o;
    o.u[0] = pkbf(a.x, a.y); o.u[1] = pkbf(a.z, a.w);
    o.u[2] = pkbf(b.x, b.y); o.u[3] = pkbf(b.z, b.w);
    *reinterpret_cast<us8*>(d + i) = o.v;
  } else {
    int j = bid - 6144;
    int mat = j >> 10, rem = j & 1023;
    int kt = (rem >> 5) * 32, nt = (rem & 31) * 32;
    const float* W = (mat == 0) ? Wq : (mat == 1) ? Wk : (mat == 2) ? Wv : Wo;
    unsigned short* oh = wthi + ((size_t)mat << 20);
    unsigned short* ol = wtlo + ((size_t)mat << 20);
    int i = threadIdx.x >> 5;
    int jj = threadIdx.x & 31;
#pragma unroll
    for (int ii = 0; ii < 4; ++ii) {
      int r = i + ii * 8;
      ls[r][jj] = W[(size_t)(kt + r) * D_MODEL + nt + jj];
    }
    __syncthreads();
#pragma unroll
    for (int ii = 0; ii < 4; ++ii) {
      int r = i + ii * 8;
      float v = ls[jj][r];
      if (mat == 0) v *= QSCALE;
      unsigned short h = f2bf(v);
      size_t o = (size_t)(nt + r) * D_MODEL + kt + jj;
      oh[o] = h;
      if (mat == 3) ol[o] = f2bf(v - bf2f(h));
    }
  }
}

// ---------------- proj GEMM (hi-only): C = A @ W^T + bias, 3 epilogues ----------------
__global__ __launch_bounds__(256, 3) void gemm_kernel(
    const unsigned short* __restrict__ A0, const unsigned short* __restrict__ A1,
    const unsigned short* __restrict__ A2, const unsigned short* __restrict__ wth,
    const float* __restrict__ b0, const float* __restrict__ b1,
    const float* __restrict__ b2,
    unsigned short* __restrict__ qh, unsigned short* __restrict__ kh,
    unsigned short* __restrict__ vt) {
  int z = blockIdx.z;
  const unsigned short* A = (z == 0) ? A0 : (z == 1) ? A1 : A2;
  const unsigned short* Bh = wth + ((size_t)z << 20);
  const float* bias = (z == 0) ? b0 : (z == 1) ? b1 : b2;
  float bsc = (z == 0) ? QSCALE : 1.0f;

  int bm = blockIdx.y, bn = blockIdx.x;
  int tid = threadIdx.x, lane = tid & 63, w = tid >> 6;
  int wr = w >> 1, wc = w & 1, l16 = lane & 15, l4 = lane >> 4;

  __shared__ unsigned short As[2][128 * 32];
  __shared__ unsigned short Bsh[2][128 * 32];

  const unsigned short* Ab = A + (size_t)(bm * 128) * D_MODEL;
  const unsigned short* Bhb = Bh + (size_t)(bn * 128) * D_MODEL;

  int r0 = tid >> 2, g0 = tid & 3;
  int r1 = (256 + tid) >> 2, g1 = tid & 3;
  int s0 = (r0 ^ (r0 >> 2)) & 3, s1 = (r1 ^ (r1 >> 2)) & 3;
  size_t so0 = (size_t)r0 * D_MODEL + ((g0 ^ s0) * 8);
  size_t so1 = (size_t)r1 * D_MODEL + ((g1 ^ s1) * 8);
  int ld0 = (w * 64) * 8;
  int ld1 = (256 + w * 64) * 8;

  int offA[4], offB[4];
#pragma unroll
  for (int m = 0; m < 4; ++m) {
    int row = wr * 64 + m * 16 + l16;
    int sw = (row ^ (row >> 2)) & 3;
    offA[m] = row * 32 + ((l4 ^ sw)) * 8;
  }
#pragma unroll
  for (int n = 0; n < 4; ++n) {
    int row = wc * 64 + n * 16 + l16;
    int sw = (row ^ (row >> 2)) & 3;
    offB[n] = row * 32 + ((l4 ^ sw)) * 8;
  }

  f4 acc[4][4];
  const f4 zf = {0.f, 0.f, 0.f, 0.f};
#pragma unroll
  for (int m = 0; m < 4; ++m)
#pragma unroll
    for (int n = 0; n < 4; ++n) acc[m][n] = zf;

  gl16(Ab + so0, &As[0][ld0]);  gl16(Ab + so1, &As[0][ld1]);
  gl16(Bhb + so0, &Bsh[0][ld0]); gl16(Bhb + so1, &Bsh[0][ld1]);
  __syncthreads();

  int cur = 0;
  for (int i = 0; i < 32; ++i) {
    if (i < 31) {
      int ktn = (i + 1) * 32;
      gl16(Ab + ktn + so0, &As[cur ^ 1][ld0]);  gl16(Ab + ktn + so1, &As[cur ^ 1][ld1]);
      gl16(Bhb + ktn + so0, &Bsh[cur ^ 1][ld0]); gl16(Bhb + ktn + so1, &Bsh[cur ^ 1][ld1]);
    }
    bf8 a[4], bh[4];
#pragma unroll
    for (int m = 0; m < 4; ++m)
      a[m] = *reinterpret_cast<const bf8*>(&As[cur][offA[m]]);
#pragma unroll
    for (int n = 0; n < 4; ++n)
      bh[n] = *reinterpret_cast<const bf8*>(&Bsh[cur][offB[n]]);
#pragma unroll
    for (int m = 0; m < 4; ++m)
#pragma unroll
      for (int n = 0; n < 4; ++n)
        acc[m][n] = mfma16(a[m], bh[n], acc[m][n]);
    __syncthreads();
    cur ^= 1;
  }

#pragma unroll
  for (int n = 0; n < 4; ++n) {
    int col = bn * 128 + wc * 64 + n * 16 + l16;
    float bb = bias[col] * bsc;
#pragma unroll
    for (int m = 0; m < 4; ++m) {
      int row0 = bm * 128 + wr * 64 + m * 16 + l4 * 4;
      if (z == 0) {
#pragma unroll
        for (int r = 0; r < 4; ++r)
          qh[(size_t)(row0 + r) * D_MODEL + col] = f2bf(acc[m][n][r] + bb);
      } else if (z == 1) {
#pragma unroll
        for (int r = 0; r < 4; ++r)
          kh[(size_t)(row0 + r) * D_MODEL + col] = f2bf(acc[m][n][r] + bb);
      } else {
        int bb2 = row0 >> 11, ss = row0 & (SEQ - 1);
        int hh2 = col >> 6, dd = col & 63;
        union { us4 s; uint2 u; } pk4;
        pk4.u.x = pkbf(acc[m][n][0] + bb, acc[m][n][1] + bb);
        pk4.u.y = pkbf(acc[m][n][2] + bb, acc[m][n][3] + bb);
        *reinterpret_cast<us4*>(vt + ((size_t)(bb2 * NH + hh2) * HD + dd) * SEQ + ss) = pk4.s;
      }
    }
  }
}

// ---------------- out GEMM (hi+lo, fp32 out): 128x64 tile, grid (16,32)=512 ----------------
__global__ __launch_bounds__(256, 3) void out_gemm(
    const unsigned short* __restrict__ ah, const unsigned short* __restrict__ wth,
    const unsigned short* __restrict__ wtl, const float* __restrict__ bo,
    float* __restrict__ o32) {
  const unsigned short* Bh = wth + ((size_t)3 << 20);
  const unsigned short* Bl = wtl + ((size_t)3 << 20);
  int bm = blockIdx.y, bn = blockIdx.x;
  int tid = threadIdx.x, lane = tid & 63, w = tid >> 6;
  int wr = w >> 1, wc = w & 1, l16 = lane & 15, l4 = lane >> 4;

  __shared__ unsigned short As[2][128 * 32];
  __shared__ unsigned short Bsh[2][64 * 32];
  __shared__ unsigned short Bsl[2][64 * 32];

  const unsigned short* Ab = ah + (size_t)(bm * 128) * D_MODEL;
  const unsigned short* Bhb = Bh + (size_t)(bn * 64) * D_MODEL;
  const unsigned short* Blb = Bl + (size_t)(bn * 64) * D_MODEL;

  int r0 = tid >> 2, g0 = tid & 3;
  int r1 = (256 + tid) >> 2;
  int s0 = (r0 ^ (r0 >> 2)) & 3, s1 = (r1 ^ (r1 >> 2)) & 3;
  size_t so0 = (size_t)r0 * D_MODEL + ((g0 ^ s0) * 8);   // rows 0..63 (also B round)
  size_t so1 = (size_t)r1 * D_MODEL + ((g0 ^ s1) * 8);   // rows 64..127 (A only)
  int ld0 = (w * 64) * 8;
  int ld1 = (256 + w * 64) * 8;

  int offA[4], offB[2];
#pragma unroll
  for (int m = 0; m < 4; ++m) {
    int row = wr * 64 + m * 16 + l16;
    int sw = (row ^ (row >> 2)) & 3;
    offA[m] = row * 32 + ((l4 ^ sw)) * 8;
  }
#pragma unroll
  for (int n = 0; n < 2; ++n) {
    int row = wc * 32 + n * 16 + l16;
    int sw = (row ^ (row >> 2)) & 3;
    offB[n] = row * 32 + ((l4 ^ sw)) * 8;
  }

  f4 acc[4][2];
  const f4 zf = {0.f, 0.f, 0.f, 0.f};
#pragma unroll
  for (int m = 0; m < 4; ++m)
#pragma unroll
    for (int n = 0; n < 2; ++n) acc[m][n] = zf;

  gl16(Ab + so0, &As[0][ld0]); gl16(Ab + so1, &As[0][ld1]);
  gl16(Bhb + so0, &Bsh[0][ld0]);
  gl16(Blb + so0, &Bsl[0][ld0]);
  __syncthreads();

  int cur = 0;
  for (int i = 0; i < 32; ++i) {
    if (i < 31) {
      int ktn = (i + 1) * 32;
      gl16(Ab + ktn + so0, &As[cur ^ 1][ld0]); gl16(Ab + ktn + so1, &As[cur ^ 1][ld1]);
      gl16(Bhb + ktn + so0, &Bsh[cur ^ 1][ld0]);
      gl16(Blb + ktn + so0, &Bsl[cur ^ 1][ld0]);
    }
    bf8 a[4], bh[2], bl[2];
#pragma unroll
    for (int m = 0; m < 4; ++m)
      a[m] = *reinterpret_cast<const bf8*>(&As[cur][offA[m]]);
#pragma unroll
    for (int n = 0; n < 2; ++n) {
      bh[n] = *reinterpret_cast<const bf8*>(&Bsh[cur][offB[n]]);
      bl[n] = *reinterpret_cast<const bf8*>(&Bsl[cur][offB[n]]);
    }
#pragma unroll
    for (int m = 0; m < 4; ++m)
#pragma unroll
      for (int n = 0; n < 2; ++n) {
        acc[m][n] = mfma16(a[m], bh[n], acc[m][n]);
        acc[m][n] = mfma16(a[m], bl[n], acc[m][n]);
      }
    __syncthreads();
    cur ^= 1;
  }

#pragma unroll
  for (int n = 0; n < 2; ++n) {
    int col = bn * 64 + wc * 32 + n * 16 + l16;
    float bb = bo[col];
#pragma unroll
    for (int m = 0; m < 4; ++m) {
      int row0 = bm * 128 + wr * 64 + m * 16 + l4 * 4;
#pragma unroll
      for (int r = 0; r < 4; ++r)
        o32[(size_t)(row0 + r) * D_MODEL + col] = acc[m][n][r] + bb;
    }
  }
}

// ---------------- flash attention: r8 body, KVBLK=128 staging (half the barriers) ----------------
// 512 blocks (2/CU), 4 waves, wave owns 32 q-rows. Per staged tile: 128 keys
// (K 16KB [128k][64d] + V^T 16KB [64d][128k]) double-buffered = 64KB LDS.
// Compute runs the IDENTICAL 64-key body twice (h2=0,1) -> arithmetic order
// unchanged vs r8/r9; only barrier/drain count halves (32 -> 16).
__global__ __launch_bounds__(256) void attn_kernel(
    const unsigned short* __restrict__ qh, const unsigned short* __restrict__ kh,
    const unsigned short* __restrict__ vt, unsigned short* __restrict__ aout) {
  // XCD-aware bijective swizzle: 512 blocks, 8 XCDs -> 64 contiguous per XCD
  int orig = blockIdx.x + (blockIdx.y << 4) + (blockIdx.z << 8);
  int swz = ((orig & 7) << 6) + (orig >> 3);
  int qt = swz & 15, h = (swz >> 4) & 15, b = swz >> 8;

  int tid = threadIdx.x;
  int lane = tid & 63, w = tid >> 6;
  int l16 = lane & 15, l4 = lane >> 4;
  int l8r = lane >> 3, l8c = lane & 7;

  __shared__ unsigned short lds[32768];   // [2][8192] K + [2][8192] V^T (64KB)

  const unsigned short* Kh = kh + (size_t)b * SEQ * D_MODEL + h * HD;
  const unsigned short* Vt = vt + (size_t)(b * NH + h) * HD * SEQ;

  // q B-frags: rows qt*128 + w*32 + m*16 + l16
  bf8 qf[2][2];
#pragma unroll
  for (int m = 0; m < 2; ++m) {
    size_t qo = (size_t)(b * SEQ + qt * 128 + w * 32 + m * 16 + l16) * D_MODEL + h * HD + l4 * 8;
    qf[m][0] = *reinterpret_cast<const bf8*>(qh + qo);
    qf[m][1] = *reinterpret_cast<const bf8*>(qh + qo + 32);
  }
  bf8 ones;
#pragma unroll
  for (int j = 0; j < 8; ++j) ones[j] = (short)0x3F80;

  const f4 zf = {0.f, 0.f, 0.f, 0.f};
  f4 acc[2][4];
  f4 accs[2] = {zf, zf};
  float mr[2] = {0.f, 0.f};
#pragma unroll
  for (int m = 0; m < 2; ++m)
#pragma unroll
    for (int nt = 0; nt < 4; ++nt) acc[m][nt] = zf;

  const int sgr = (l8c ^ l8r) * 8;     // K-staging pre-swizzled source granule
  const int swk = l16 & 7;
  const int vsub = ((l4 & 1) << 2);
  // V staging coords: chunk covers 4 d-rows x 16 granules; lane -> row/pos/src-granule
  const int vrow_in = lane >> 4;       // 0..3 within chunk
  const int vpos = lane & 15;
  // per-wave chunk ids: s = w*4 + j, j=0..3 (K and V each 16 chunks of 1KB)

  // ---- stage tile 0 (128 keys) into buf 0 ----
  {
#pragma unroll
    for (int j = 0; j < 4; ++j) {
      int s = w * 4 + j;
      gl16(Kh + (size_t)(8 * s + l8r) * D_MODEL + sgr, &lds[0 + s * 512]);
      int row = 4 * s + vrow_in;
      int g = ((lane & 7) ^ (row & 7)) | (lane & 8);
      gl16(Vt + (size_t)row * SEQ + g * 8, &lds[16384 + s * 512]);
    }
  }
  __syncthreads();

  int cur = 0;
  for (int kt = 0; kt < SEQ / 128; ++kt) {
    if (kt < SEQ / 128 - 1) {
      int k0n = (kt + 1) * 128;
      unsigned short* kd = &lds[(cur ^ 1) * 8192];
      unsigned short* vd = &lds[16384 + (cur ^ 1) * 8192];
#pragma unroll
      for (int j = 0; j < 4; ++j) {
        int s = w * 4 + j;
        gl16(Kh + (size_t)(k0n + 8 * s + l8r) * D_MODEL + sgr, kd + s * 512);
        int row = 4 * s + vrow_in;
        int g = ((lane & 7) ^ (row & 7)) | (lane & 8);
        gl16(Vt + (size_t)row * SEQ + k0n + g * 8, vd + s * 512);
      }
    }
    const unsigned short* khb = &lds[cur * 8192];
    const unsigned short* vlb = &lds[16384 + cur * 8192];

#pragma unroll
    for (int h2 = 0; h2 < 2; ++h2) {
      const unsigned short* khh = khb + h2 * 4096;   // rows h2*64.. of [128][64]
      // K A-frags: A[row=key(half-local), k=d]
      bf8 kb[4][2];
#pragma unroll
      for (int c = 0; c < 4; ++c) {
        int row = c * 16 + l16;
        kb[c][0] = *reinterpret_cast<const bf8*>(&khh[row * 64 + ((l4 ^ swk) * 8)]);
        kb[c][1] = *reinterpret_cast<const bf8*>(&khh[row * 64 + (((4 + l4) ^ swk) * 8)]);
      }
      f4 sc[2][4];
      __builtin_amdgcn_s_setprio(1);
#pragma unroll
      for (int m = 0; m < 2; ++m)
#pragma unroll
        for (int c = 0; c < 4; ++c) {
          f4 sv = zf;
          sv = mfma16(kb[c][0], qf[m][0], sv);
          sv = mfma16(kb[c][1], qf[m][1], sv);
          sc[m][c] = sv;
        }
      __builtin_amdgcn_s_setprio(0);
      // V chunks: rows d=nt*16+l16 of [64][128]; granule pos = (gvc^swk) + 8*h2
      uint2 vdr[4][4];
#pragma unroll
      for (int c = 0; c < 4; ++c) {
        int gvc = 2 * c + (l4 >> 1);
        int voff = (((gvc ^ swk) + 8 * h2) << 3) + vsub;
#pragma unroll
        for (int nt = 0; nt < 4; ++nt)
          vdr[c][nt] = *reinterpret_cast<const uint2*>(&vlb[(nt * 16 + l16) * 128 + voff]);
      }
      unsigned Wp[2][4][2];
#pragma unroll
      for (int m = 0; m < 2; ++m) {
        float tc0 = fmaxf(fmaxf(sc[m][0][0], sc[m][0][1]), fmaxf(sc[m][0][2], sc[m][0][3]));
        float tc1 = fmaxf(fmaxf(sc[m][1][0], sc[m][1][1]), fmaxf(sc[m][1][2], sc[m][1][3]));
        float tc2 = fmaxf(fmaxf(sc[m][2][0], sc[m][2][1]), fmaxf(sc[m][2][2], sc[m][2][3]));
        float tc3 = fmaxf(fmaxf(sc[m][3][0], sc[m][3][1]), fmaxf(sc[m][3][2], sc[m][3][3]));
        float tm = fmaxf(fmaxf(tc0, tc1), fmaxf(tc2, tc3));
        tm = fmaxf(tm, __shfl_xor(tm, 16));
        tm = fmaxf(tm, __shfl_xor(tm, 32));
        if (__any(tm > mr[m] + 8.0f)) {
          float mn = fmaxf(mr[m], tm);
          float al = ex2(mr[m] - mn);
          mr[m] = mn;
          accs[m][0] *= al; accs[m][1] *= al; accs[m][2] *= al; accs[m][3] *= al;
#pragma unroll
          for (int nt = 0; nt < 4; ++nt) {
            acc[m][nt][0] *= al; acc[m][nt][1] *= al;
            acc[m][nt][2] *= al; acc[m][nt][3] *= al;
          }
        }
#pragma unroll
        for (int c = 0; c < 4; ++c) {
          float p0 = ex2(sc[m][c][0] - mr[m]);
          float p1 = ex2(sc[m][c][1] - mr[m]);
          float p2 = ex2(sc[m][c][2] - mr[m]);
          float p3 = ex2(sc[m][c][3] - mr[m]);
          Wp[m][c][0] = pkbf(p0, p1);
          Wp[m][c][1] = pkbf(p2, p3);
        }
      }
      __builtin_amdgcn_s_setprio(1);
#pragma unroll
      for (int c = 0; c < 4; ++c)
#pragma unroll
        for (int m = 0; m < 2; ++m) {
          union { bf8 v; unsigned u[4]; } pu;
          pu.u[0] = Wp[m][c][0]; pu.u[1] = Wp[m][c][1]; pu.u[2] = 0; pu.u[3] = 0;
          accs[m] = mfma16(ones, pu.v, accs[m]);
#pragma unroll
          for (int nt = 0; nt < 4; ++nt) {
            union { bf8 v; unsigned u[4]; } vu;
            vu.u[0] = vdr[c][nt].x; vu.u[1] = vdr[c][nt].y; vu.u[2] = 0; vu.u[3] = 0;
            acc[m][nt] = mfma16(vu.v, pu.v, acc[m][nt]);
          }
        }
      __builtin_amdgcn_s_setprio(0);
    }
    __syncthreads();
    cur ^= 1;
  }

  // epilogue: normalize, transpose O^T -> O via freed LDS
  float inv[2];
#pragma unroll
  for (int m = 0; m < 2; ++m) inv[m] = 1.0f / accs[m][0];
#pragma unroll
  for (int m = 0; m < 2; ++m) {
    int q = w * 32 + m * 16 + l16;
    int sw = (q & 7) << 3;
#pragma unroll
    for (int nt = 0; nt < 4; ++nt) {
      uint2 pw;
      pw.x = pkbf(acc[m][nt][0] * inv[m], acc[m][nt][1] * inv[m]);
      pw.y = pkbf(acc[m][nt][2] * inv[m], acc[m][nt][3] * inv[m]);
      int d0 = nt * 16 + l4 * 4;
      *reinterpret_cast<uint2*>(&lds[q * 64 + (d0 ^ sw)]) = pw;
    }
  }
  __syncthreads();
  {
    int q = tid >> 1, dh = (tid & 1) * 32, sw = (q & 7) << 3;
    size_t orow = ((size_t)(b * SEQ + qt * 128 + q)) * D_MODEL + h * HD + dh;
#pragma unroll
    for (int j = 0; j < 4; ++j) {
      us8 vv = *reinterpret_cast<const us8*>(&lds[q * 64 + ((dh + j * 8) ^ sw)]);
      *reinterpret_cast<us8*>(&aout[orow + j * 8]) = vv;
    }
  }
}

extern "C" void kernel_launch(void* const* d_in, const int* in_sizes, int n_in,
                              void* d_out, int out_size, void* d_ws, size_t ws_size,
                              hipStream_t stream) {
  const float* Q  = (const float*)d_in[0];
  const float* K  = (const float*)d_in[1];
  const float* V  = (const float*)d_in[2];
  const float* Wq = (const float*)d_in[3];
  const float* bq = (const float*)d_in[4];
  const float* Wk = (const float*)d_in[5];
  const float* bk = (const float*)d_in[6];
  const float* Wv = (const float*)d_in[7];
  const float* bv = (const float*)d_in[8];
  const float* Wo = (const float*)d_in[9];
  const float* bo = (const float*)d_in[10];
  float* out = (float*)d_out;

  // workspace (56 MB) + d_out doubles as Q/K bf16 scratch (overwritten by out_gemm)
  unsigned char* ws = (unsigned char*)d_ws;
  const size_t MB = 1024 * 1024;
  unsigned short* wthi = (unsigned short*)(ws);             // 4x W^T hi      (8 MB)
  unsigned short* wtlo = (unsigned short*)(ws + 8 * MB);    // W^T lo (mat 3) (8 MB)
  unsigned short* qh   = (unsigned short*)(ws + 16 * MB);   // q bf16 [B,S,D] (8 MB)
  unsigned short* kh   = (unsigned short*)(ws + 24 * MB);   // k bf16         (8 MB)
  unsigned short* vt   = (unsigned short*)(ws + 32 * MB);   // V^T [B,H,d,S]  (8 MB)
  unsigned short* ah   = (unsigned short*)(ws + 40 * MB);   // attn out bf16  (8 MB)
  unsigned short* vbf  = (unsigned short*)(ws + 48 * MB);   // V input bf16   (8 MB)
  unsigned short* qbf  = (unsigned short*)d_out;            // Q input bf16 (scratch)
  unsigned short* kbf  = (unsigned short*)d_out + 4 * MB;   // K input bf16 (scratch)

  prep_all<<<dim3(10240, 1, 1), 256, 0, stream>>>(Q, K, V, Wq, Wk, Wv, Wo,
                                                  qbf, kbf, vbf, wthi, wtlo);
  gemm_kernel<<<dim3(8, 32, 3), 256, 0, stream>>>(qbf, kbf, vbf, wthi,
                                                  bq, bk, bv, qh, kh, vt);
  attn_kernel<<<dim3(16, NH, NB), 256, 0, stream>>>(qh, kh, vt, ah);
  out_gemm<<<dim3(16, 32, 1), 256, 0, stream>>>(ah, wthi, wtlo, bo, out);
}

// Round 11
// 142.290 us; speedup vs baseline: 1.6269x; 1.0557x over previous
//
#include <hip/hip_runtime.h>
#include <cstdint>
#include <cstddef>

#define D_MODEL 1024
#define HD 64
#define NH 16
#define SEQ 2048
#define NB 2

typedef __attribute__((ext_vector_type(8))) short bf8;           // 8 bf16 (4 VGPR)
typedef __attribute__((ext_vector_type(8))) unsigned short us8;
typedef __attribute__((ext_vector_type(4))) unsigned short us4;
typedef __attribute__((ext_vector_type(4))) float f4;

__device__ __forceinline__ float bf2f(unsigned short u) {
  union { unsigned int i; float f; } c; c.i = ((unsigned int)u) << 16; return c.f;
}
__device__ __forceinline__ unsigned short f2bf(float x) {
  union { float f; unsigned int i; } c; c.f = x;
  unsigned int r = (c.i + 0x7FFFu + ((c.i >> 16) & 1u)) >> 16;   // RNE
  return (unsigned short)r;
}
// packed f32x2 -> bf16x2 (RNE), single HW op
__device__ __forceinline__ unsigned int pkbf(float lo, float hi) {
  unsigned int r;
  asm("v_cvt_pk_bf16_f32 %0, %1, %2" : "=v"(r) : "v"(lo), "v"(hi));
  return r;
}
// exp2 via v_exp_f32 (D = 2^S0)
__device__ __forceinline__ float ex2(float x) {
  float r;
  asm("v_exp_f32 %0, %1" : "=v"(r) : "v"(x));
  return r;
}
__device__ __forceinline__ f4 mfma16(bf8 a, bf8 b, f4 c) {
  return __builtin_amdgcn_mfma_f32_16x16x32_bf16(a, b, c, 0, 0, 0);
}
// async global->LDS, 16B per lane; LDS dest = wave-uniform base + lane*16
__device__ __forceinline__ void gl16(const unsigned short* g, unsigned short* l) {
  __builtin_amdgcn_global_load_lds(
      (const __attribute__((address_space(1))) unsigned int*)g,
      (__attribute__((address_space(3))) unsigned int*)l, 16, 0, 0);
}

#define QSCALE (0.125f * 1.44269504088896f)   // 1/sqrt(64) * log2(e)

// ---------------- fused prep: input bf16 convert + weight transpose/split ----------------
__global__ __launch_bounds__(256) void prep_all(
    const float* __restrict__ Q, const float* __restrict__ K, const float* __restrict__ V,
    const float* __restrict__ Wq, const float* __restrict__ Wk,
    const float* __restrict__ Wv, const float* __restrict__ Wo,
    unsigned short* __restrict__ dq, unsigned short* __restrict__ dk,
    unsigned short* __restrict__ dv,
    unsigned short* __restrict__ wthi, unsigned short* __restrict__ wtlo) {
  int bid = blockIdx.x;
  __shared__ float ls[32][33];
  if (bid < 6144) {
    int z = bid >> 11, x = bid & 2047;
    const float* s = (z == 0) ? Q : (z == 1) ? K : V;
    unsigned short* d = (z == 0) ? dq : (z == 1) ? dk : dv;
    size_t i = ((size_t)x * 256 + threadIdx.x) * 8;
    float4 a = *reinterpret_cast<const float4*>(s + i);
    float4 b = *reinterpret_cast<const float4*>(s + i + 4);
    union { us8 v; unsigned int u[4]; } o;
    o.u[0] = pkbf(a.x, a.y); o.u[1] = pkbf(a.z, a.w);
    o.u[2] = pkbf(b.x, b.y); o.u[3] = pkbf(b.z, b.w);
    *reinterpret_cast<us8*>(d + i) = o.v;
  } else {
    int j = bid - 6144;
    int mat = j >> 10, rem = j & 1023;
    int kt = (rem >> 5) * 32, nt = (rem & 31) * 32;
    const float* W = (mat == 0) ? Wq : (mat == 1) ? Wk : (mat == 2) ? Wv : Wo;
    unsigned short* oh = wthi + ((size_t)mat << 20);
    unsigned short* ol = wtlo + ((size_t)mat << 20);
    int i = threadIdx.x >> 5;
    int jj = threadIdx.x & 31;
#pragma unroll
    for (int ii = 0; ii < 4; ++ii) {
      int r = i + ii * 8;
      ls[r][jj] = W[(size_t)(kt + r) * D_MODEL + nt + jj];
    }
    __syncthreads();
#pragma unroll
    for (int ii = 0; ii < 4; ++ii) {
      int r = i + ii * 8;
      float v = ls[jj][r];
      if (mat == 0) v *= QSCALE;
      unsigned short h = f2bf(v);
      size_t o = (size_t)(nt + r) * D_MODEL + kt + jj;
      oh[o] = h;
      if (mat == 3) ol[o] = f2bf(v - bf2f(h));
    }
  }
}

// ---------------- proj GEMM (hi-only): C = A @ W^T + bias, 3 epilogues ----------------
__global__ __launch_bounds__(256, 3) void gemm_kernel(
    const unsigned short* __restrict__ A0, const unsigned short* __restrict__ A1,
    const unsigned short* __restrict__ A2, const unsigned short* __restrict__ wth,
    const float* __restrict__ b0, const float* __restrict__ b1,
    const float* __restrict__ b2,
    unsigned short* __restrict__ qh, unsigned short* __restrict__ kh,
    unsigned short* __restrict__ vt) {
  int z = blockIdx.z;
  const unsigned short* A = (z == 0) ? A0 : (z == 1) ? A1 : A2;
  const unsigned short* Bh = wth + ((size_t)z << 20);
  const float* bias = (z == 0) ? b0 : (z == 1) ? b1 : b2;
  float bsc = (z == 0) ? QSCALE : 1.0f;

  int bm = blockIdx.y, bn = blockIdx.x;
  int tid = threadIdx.x, lane = tid & 63, w = tid >> 6;
  int wr = w >> 1, wc = w & 1, l16 = lane & 15, l4 = lane >> 4;

  __shared__ unsigned short As[2][128 * 32];
  __shared__ unsigned short Bsh[2][128 * 32];

  const unsigned short* Ab = A + (size_t)(bm * 128) * D_MODEL;
  const unsigned short* Bhb = Bh + (size_t)(bn * 128) * D_MODEL;

  int r0 = tid >> 2, g0 = tid & 3;
  int r1 = (256 + tid) >> 2, g1 = tid & 3;
  int s0 = (r0 ^ (r0 >> 2)) & 3, s1 = (r1 ^ (r1 >> 2)) & 3;
  size_t so0 = (size_t)r0 * D_MODEL + ((g0 ^ s0) * 8);
  size_t so1 = (size_t)r1 * D_MODEL + ((g1 ^ s1) * 8);
  int ld0 = (w * 64) * 8;
  int ld1 = (256 + w * 64) * 8;

  int offA[4], offB[4];
#pragma unroll
  for (int m = 0; m < 4; ++m) {
    int row = wr * 64 + m * 16 + l16;
    int sw = (row ^ (row >> 2)) & 3;
    offA[m] = row * 32 + ((l4 ^ sw)) * 8;
  }
#pragma unroll
  for (int n = 0; n < 4; ++n) {
    int row = wc * 64 + n * 16 + l16;
    int sw = (row ^ (row >> 2)) & 3;
    offB[n] = row * 32 + ((l4 ^ sw)) * 8;
  }

  f4 acc[4][4];
  const f4 zf = {0.f, 0.f, 0.f, 0.f};
#pragma unroll
  for (int m = 0; m < 4; ++m)
#pragma unroll
    for (int n = 0; n < 4; ++n) acc[m][n] = zf;

  gl16(Ab + so0, &As[0][ld0]);  gl16(Ab + so1, &As[0][ld1]);
  gl16(Bhb + so0, &Bsh[0][ld0]); gl16(Bhb + so1, &Bsh[0][ld1]);
  __syncthreads();

  int cur = 0;
  for (int i = 0; i < 32; ++i) {
    if (i < 31) {
      int ktn = (i + 1) * 32;
      gl16(Ab + ktn + so0, &As[cur ^ 1][ld0]);  gl16(Ab + ktn + so1, &As[cur ^ 1][ld1]);
      gl16(Bhb + ktn + so0, &Bsh[cur ^ 1][ld0]); gl16(Bhb + ktn + so1, &Bsh[cur ^ 1][ld1]);
    }
    bf8 a[4], bh[4];
#pragma unroll
    for (int m = 0; m < 4; ++m)
      a[m] = *reinterpret_cast<const bf8*>(&As[cur][offA[m]]);
#pragma unroll
    for (int n = 0; n < 4; ++n)
      bh[n] = *reinterpret_cast<const bf8*>(&Bsh[cur][offB[n]]);
#pragma unroll
    for (int m = 0; m < 4; ++m)
#pragma unroll
      for (int n = 0; n < 4; ++n)
        acc[m][n] = mfma16(a[m], bh[n], acc[m][n]);
    __syncthreads();
    cur ^= 1;
  }

#pragma unroll
  for (int n = 0; n < 4; ++n) {
    int col = bn * 128 + wc * 64 + n * 16 + l16;
    float bb = bias[col] * bsc;
#pragma unroll
    for (int m = 0; m < 4; ++m) {
      int row0 = bm * 128 + wr * 64 + m * 16 + l4 * 4;
      if (z == 0) {
#pragma unroll
        for (int r = 0; r < 4; ++r)
          qh[(size_t)(row0 + r) * D_MODEL + col] = f2bf(acc[m][n][r] + bb);
      } else if (z == 1) {
#pragma unroll
        for (int r = 0; r < 4; ++r)
          kh[(size_t)(row0 + r) * D_MODEL + col] = f2bf(acc[m][n][r] + bb);
      } else {
        int bb2 = row0 >> 11, ss = row0 & (SEQ - 1);
        int hh2 = col >> 6, dd = col & 63;
        union { us4 s; uint2 u; } pk4;
        pk4.u.x = pkbf(acc[m][n][0] + bb, acc[m][n][1] + bb);
        pk4.u.y = pkbf(acc[m][n][2] + bb, acc[m][n][3] + bb);
        *reinterpret_cast<us4*>(vt + ((size_t)(bb2 * NH + hh2) * HD + dd) * SEQ + ss) = pk4.s;
      }
    }
  }
}

// ---------------- out GEMM (hi+lo, fp32 out): 128x64 tile, grid (16,32)=512 ----------------
__global__ __launch_bounds__(256, 3) void out_gemm(
    const unsigned short* __restrict__ ah, const unsigned short* __restrict__ wth,
    const unsigned short* __restrict__ wtl, const float* __restrict__ bo,
    float* __restrict__ o32) {
  const unsigned short* Bh = wth + ((size_t)3 << 20);
  const unsigned short* Bl = wtl + ((size_t)3 << 20);
  int bm = blockIdx.y, bn = blockIdx.x;
  int tid = threadIdx.x, lane = tid & 63, w = tid >> 6;
  int wr = w >> 1, wc = w & 1, l16 = lane & 15, l4 = lane >> 4;

  __shared__ unsigned short As[2][128 * 32];
  __shared__ unsigned short Bsh[2][64 * 32];
  __shared__ unsigned short Bsl[2][64 * 32];

  const unsigned short* Ab = ah + (size_t)(bm * 128) * D_MODEL;
  const unsigned short* Bhb = Bh + (size_t)(bn * 64) * D_MODEL;
  const unsigned short* Blb = Bl + (size_t)(bn * 64) * D_MODEL;

  int r0 = tid >> 2, g0 = tid & 3;
  int r1 = (256 + tid) >> 2;
  int s0 = (r0 ^ (r0 >> 2)) & 3, s1 = (r1 ^ (r1 >> 2)) & 3;
  size_t so0 = (size_t)r0 * D_MODEL + ((g0 ^ s0) * 8);   // rows 0..63 (also B round)
  size_t so1 = (size_t)r1 * D_MODEL + ((g0 ^ s1) * 8);   // rows 64..127 (A only)
  int ld0 = (w * 64) * 8;
  int ld1 = (256 + w * 64) * 8;

  int offA[4], offB[2];
#pragma unroll
  for (int m = 0; m < 4; ++m) {
    int row = wr * 64 + m * 16 + l16;
    int sw = (row ^ (row >> 2)) & 3;
    offA[m] = row * 32 + ((l4 ^ sw)) * 8;
  }
#pragma unroll
  for (int n = 0; n < 2; ++n) {
    int row = wc * 32 + n * 16 + l16;
    int sw = (row ^ (row >> 2)) & 3;
    offB[n] = row * 32 + ((l4 ^ sw)) * 8;
  }

  f4 acc[4][2];
  const f4 zf = {0.f, 0.f, 0.f, 0.f};
#pragma unroll
  for (int m = 0; m < 4; ++m)
#pragma unroll
    for (int n = 0; n < 2; ++n) acc[m][n] = zf;

  gl16(Ab + so0, &As[0][ld0]); gl16(Ab + so1, &As[0][ld1]);
  gl16(Bhb + so0, &Bsh[0][ld0]);
  gl16(Blb + so0, &Bsl[0][ld0]);
  __syncthreads();

  int cur = 0;
  for (int i = 0; i < 32; ++i) {
    if (i < 31) {
      int ktn = (i + 1) * 32;
      gl16(Ab + ktn + so0, &As[cur ^ 1][ld0]); gl16(Ab + ktn + so1, &As[cur ^ 1][ld1]);
      gl16(Bhb + ktn + so0, &Bsh[cur ^ 1][ld0]);
      gl16(Blb + ktn + so0, &Bsl[cur ^ 1][ld0]);
    }
    bf8 a[4], bh[2], bl[2];
#pragma unroll
    for (int m = 0; m < 4; ++m)
      a[m] = *reinterpret_cast<const bf8*>(&As[cur][offA[m]]);
#pragma unroll
    for (int n = 0; n < 2; ++n) {
      bh[n] = *reinterpret_cast<const bf8*>(&Bsh[cur][offB[n]]);
      bl[n] = *reinterpret_cast<const bf8*>(&Bsl[cur][offB[n]]);
    }
#pragma unroll
    for (int m = 0; m < 4; ++m)
#pragma unroll
      for (int n = 0; n < 2; ++n) {
        acc[m][n] = mfma16(a[m], bh[n], acc[m][n]);
        acc[m][n] = mfma16(a[m], bl[n], acc[m][n]);
      }
    __syncthreads();
    cur ^= 1;
  }

#pragma unroll
  for (int n = 0; n < 2; ++n) {
    int col = bn * 64 + wc * 32 + n * 16 + l16;
    float bb = bo[col];
#pragma unroll
    for (int m = 0; m < 4; ++m) {
      int row0 = bm * 128 + wr * 64 + m * 16 + l4 * 4;
#pragma unroll
      for (int r = 0; r < 4; ++r)
        o32[(size_t)(row0 + r) * D_MODEL + col] = acc[m][n][r] + bb;
    }
  }
}

// ---------------- flash attention: KVBLK=128, PAIRED-WINDOW PV (full K=32 MFMAs) ----------------
// 512 blocks (2/CU), 4 waves, wave owns 32 q-rows. Swapped QK^T; softmax in-register.
// PV packs TWO 16-key windows into one K=32 MFMA (k-slots are labels: both operands
// use the same key->slot map, so the contraction is exact). 36 MFMA/wave-step vs 56.
__global__ __launch_bounds__(256) void attn_kernel(
    const unsigned short* __restrict__ qh, const unsigned short* __restrict__ kh,
    const unsigned short* __restrict__ vt, unsigned short* __restrict__ aout) {
  // XCD-aware bijective swizzle: 512 blocks, 8 XCDs -> 64 contiguous per XCD
  int orig = blockIdx.x + (blockIdx.y << 4) + (blockIdx.z << 8);
  int swz = ((orig & 7) << 6) + (orig >> 3);
  int qt = swz & 15, h = (swz >> 4) & 15, b = swz >> 8;

  int tid = threadIdx.x;
  int lane = tid & 63, w = tid >> 6;
  int l16 = lane & 15, l4 = lane >> 4;
  int l8r = lane >> 3, l8c = lane & 7;

  __shared__ unsigned short lds[32768];   // [2][8192] K + [2][8192] V^T (64KB)

  const unsigned short* Kh = kh + (size_t)b * SEQ * D_MODEL + h * HD;
  const unsigned short* Vt = vt + (size_t)(b * NH + h) * HD * SEQ;

  // q B-frags: rows qt*128 + w*32 + m*16 + l16
  bf8 qf[2][2];
#pragma unroll
  for (int m = 0; m < 2; ++m) {
    size_t qo = (size_t)(b * SEQ + qt * 128 + w * 32 + m * 16 + l16) * D_MODEL + h * HD + l4 * 8;
    qf[m][0] = *reinterpret_cast<const bf8*>(qh + qo);
    qf[m][1] = *reinterpret_cast<const bf8*>(qh + qo + 32);
  }
  bf8 ones;
#pragma unroll
  for (int j = 0; j < 8; ++j) ones[j] = (short)0x3F80;

  const f4 zf = {0.f, 0.f, 0.f, 0.f};
  f4 acc[2][4];
  f4 accs[2] = {zf, zf};
  float mr[2] = {0.f, 0.f};
#pragma unroll
  for (int m = 0; m < 2; ++m)
#pragma unroll
    for (int nt = 0; nt < 4; ++nt) acc[m][nt] = zf;

  const int sgr = (l8c ^ l8r) * 8;     // K-staging pre-swizzled source granule
  const int swk = l16 & 7;
  const int vsub = ((l4 & 1) << 2);
  const int vrow_in = lane >> 4;       // 0..3 within V staging chunk

  // ---- stage tile 0 (128 keys) into buf 0 ----
  {
#pragma unroll
    for (int j = 0; j < 4; ++j) {
      int s = w * 4 + j;
      gl16(Kh + (size_t)(8 * s + l8r) * D_MODEL + sgr, &lds[0 + s * 512]);
      int row = 4 * s + vrow_in;
      int g = ((lane & 7) ^ (row & 7)) | (lane & 8);
      gl16(Vt + (size_t)row * SEQ + g * 8, &lds[16384 + s * 512]);
    }
  }
  __syncthreads();

  int cur = 0;
  for (int kt = 0; kt < SEQ / 128; ++kt) {
    if (kt < SEQ / 128 - 1) {
      int k0n = (kt + 1) * 128;
      unsigned short* kd = &lds[(cur ^ 1) * 8192];
      unsigned short* vd = &lds[16384 + (cur ^ 1) * 8192];
#pragma unroll
      for (int j = 0; j < 4; ++j) {
        int s = w * 4 + j;
        gl16(Kh + (size_t)(k0n + 8 * s + l8r) * D_MODEL + sgr, kd + s * 512);
        int row = 4 * s + vrow_in;
        int g = ((lane & 7) ^ (row & 7)) | (lane & 8);
        gl16(Vt + (size_t)row * SEQ + k0n + g * 8, vd + s * 512);
      }
    }
    const unsigned short* khb = &lds[cur * 8192];
    const unsigned short* vlb = &lds[16384 + cur * 8192];

#pragma unroll
    for (int h2 = 0; h2 < 2; ++h2) {
      const unsigned short* khh = khb + h2 * 4096;   // rows h2*64.. of [128][64]
      // K A-frags: A[row=key(half-local), k=d]
      bf8 kb[4][2];
#pragma unroll
      for (int c = 0; c < 4; ++c) {
        int row = c * 16 + l16;
        kb[c][0] = *reinterpret_cast<const bf8*>(&khh[row * 64 + ((l4 ^ swk) * 8)]);
        kb[c][1] = *reinterpret_cast<const bf8*>(&khh[row * 64 + (((4 + l4) ^ swk) * 8)]);
      }
      f4 sc[2][4];
      __builtin_amdgcn_s_setprio(1);
#pragma unroll
      for (int m = 0; m < 2; ++m)
#pragma unroll
        for (int c = 0; c < 4; ++c) {
          f4 sv = zf;
          sv = mfma16(kb[c][0], qf[m][0], sv);
          sv = mfma16(kb[c][1], qf[m][1], sv);
          sc[m][c] = sv;
        }
      __builtin_amdgcn_s_setprio(0);
      // V chunks: rows d=nt*16+l16 of [64][128]; granule pos = (gvc^swk) + 8*h2
      uint2 vdr[4][4];
#pragma unroll
      for (int c = 0; c < 4; ++c) {
        int gvc = 2 * c + (l4 >> 1);
        int voff = (((gvc ^ swk) + 8 * h2) << 3) + vsub;
#pragma unroll
        for (int nt = 0; nt < 4; ++nt)
          vdr[c][nt] = *reinterpret_cast<const uint2*>(&vlb[(nt * 16 + l16) * 128 + voff]);
      }
      unsigned Wp[2][4][2];
#pragma unroll
      for (int m = 0; m < 2; ++m) {
        float tc0 = fmaxf(fmaxf(sc[m][0][0], sc[m][0][1]), fmaxf(sc[m][0][2], sc[m][0][3]));
        float tc1 = fmaxf(fmaxf(sc[m][1][0], sc[m][1][1]), fmaxf(sc[m][1][2], sc[m][1][3]));
        float tc2 = fmaxf(fmaxf(sc[m][2][0], sc[m][2][1]), fmaxf(sc[m][2][2], sc[m][2][3]));
        float tc3 = fmaxf(fmaxf(sc[m][3][0], sc[m][3][1]), fmaxf(sc[m][3][2], sc[m][3][3]));
        float tm = fmaxf(fmaxf(tc0, tc1), fmaxf(tc2, tc3));
        tm = fmaxf(tm, __shfl_xor(tm, 16));
        tm = fmaxf(tm, __shfl_xor(tm, 32));
        if (__any(tm > mr[m] + 8.0f)) {
          float mn = fmaxf(mr[m], tm);
          float al = ex2(mr[m] - mn);
          mr[m] = mn;
          accs[m][0] *= al; accs[m][1] *= al; accs[m][2] *= al; accs[m][3] *= al;
#pragma unroll
          for (int nt = 0; nt < 4; ++nt) {
            acc[m][nt][0] *= al; acc[m][nt][1] *= al;
            acc[m][nt][2] *= al; acc[m][nt][3] *= al;
          }
        }
#pragma unroll
        for (int c = 0; c < 4; ++c) {
          float p0 = ex2(sc[m][c][0] - mr[m]);
          float p1 = ex2(sc[m][c][1] - mr[m]);
          float p2 = ex2(sc[m][c][2] - mr[m]);
          float p3 = ex2(sc[m][c][3] - mr[m]);
          Wp[m][c][0] = pkbf(p0, p1);
          Wp[m][c][1] = pkbf(p2, p3);
        }
      }
      // PV + denominator: two 16-key windows packed per K=32 MFMA (slots 0-3 = c0,
      // slots 4-7 = c1; P and V use the same key->slot map -> exact contraction)
      __builtin_amdgcn_s_setprio(1);
#pragma unroll
      for (int cp = 0; cp < 2; ++cp) {
        int c0 = cp * 2, c1 = cp * 2 + 1;
#pragma unroll
        for (int m = 0; m < 2; ++m) {
          union { bf8 v; unsigned u[4]; } pu;
          pu.u[0] = Wp[m][c0][0]; pu.u[1] = Wp[m][c0][1];
          pu.u[2] = Wp[m][c1][0]; pu.u[3] = Wp[m][c1][1];
          accs[m] = mfma16(ones, pu.v, accs[m]);
#pragma unroll
          for (int nt = 0; nt < 4; ++nt) {
            union { bf8 v; unsigned u[4]; } vu;
            vu.u[0] = vdr[c0][nt].x; vu.u[1] = vdr[c0][nt].y;
            vu.u[2] = vdr[c1][nt].x; vu.u[3] = vdr[c1][nt].y;
            acc[m][nt] = mfma16(vu.v, pu.v, acc[m][nt]);
          }
        }
      }
      __builtin_amdgcn_s_setprio(0);
    }
    __syncthreads();
    cur ^= 1;
  }

  // epilogue: normalize, transpose O^T -> O via freed LDS
  float inv[2];
#pragma unroll
  for (int m = 0; m < 2; ++m) inv[m] = 1.0f / accs[m][0];
#pragma unroll
  for (int m = 0; m < 2; ++m) {
    int q = w * 32 + m * 16 + l16;
    int sw = (q & 7) << 3;
#pragma unroll
    for (int nt = 0; nt < 4; ++nt) {
      uint2 pw;
      pw.x = pkbf(acc[m][nt][0] * inv[m], acc[m][nt][1] * inv[m]);
      pw.y = pkbf(acc[m][nt][2] * inv[m], acc[m][nt][3] * inv[m]);
      int d0 = nt * 16 + l4 * 4;
      *reinterpret_cast<uint2*>(&lds[q * 64 + (d0 ^ sw)]) = pw;
    }
  }
  __syncthreads();
  {
    int q = tid >> 1, dh = (tid & 1) * 32, sw = (q & 7) << 3;
    size_t orow = ((size_t)(b * SEQ + qt * 128 + q)) * D_MODEL + h * HD + dh;
#pragma unroll
    for (int j = 0; j < 4; ++j) {
      us8 vv = *reinterpret_cast<const us8*>(&lds[q * 64 + ((dh + j * 8) ^ sw)]);
      *reinterpret_cast<us8*>(&aout[orow + j * 8]) = vv;
    }
  }
}

extern "C" void kernel_launch(void* const* d_in, const int* in_sizes, int n_in,
                              void* d_out, int out_size, void* d_ws, size_t ws_size,
                              hipStream_t stream) {
  const float* Q  = (const float*)d_in[0];
  const float* K  = (const float*)d_in[1];
  const float* V  = (const float*)d_in[2];
  const float* Wq = (const float*)d_in[3];
  const float* bq = (const float*)d_in[4];
  const float* Wk = (const float*)d_in[5];
  const float* bk = (const float*)d_in[6];
  const float* Wv = (const float*)d_in[7];
  const float* bv = (const float*)d_in[8];
  const float* Wo = (const float*)d_in[9];
  const float* bo = (const float*)d_in[10];
  float* out = (float*)d_out;

  // workspace (56 MB) + d_out doubles as Q/K bf16 scratch (overwritten by out_gemm)
  unsigned char* ws = (unsigned char*)d_ws;
  const size_t MB = 1024 * 1024;
  unsigned short* wthi = (unsigned short*)(ws);             // 4x W^T hi      (8 MB)
  unsigned short* wtlo = (unsigned short*)(ws + 8 * MB);    // W^T lo (mat 3) (8 MB)
  unsigned short* qh   = (unsigned short*)(ws + 16 * MB);   // q bf16 [B,S,D] (8 MB)
  unsigned short* kh   = (unsigned short*)(ws + 24 * MB);   // k bf16         (8 MB)
  unsigned short* vt   = (unsigned short*)(ws + 32 * MB);   // V^T [B,H,d,S]  (8 MB)
  unsigned short* ah   = (unsigned short*)(ws + 40 * MB);   // attn out bf16  (8 MB)
  unsigned short* vbf  = (unsigned short*)(ws + 48 * MB);   // V input bf16   (8 MB)
  unsigned short* qbf  = (unsigned short*)d_out;            // Q input bf16 (scratch)
  unsigned short* kbf  = (unsigned short*)d_out + 4 * MB;   // K input bf16 (scratch)

  prep_all<<<dim3(10240, 1, 1), 256, 0, stream>>>(Q, K, V, Wq, Wk, Wv, Wo,
                                                  qbf, kbf, vbf, wthi, wtlo);
  gemm_kernel<<<dim3(8, 32, 3), 256, 0, stream>>>(qbf, kbf, vbf, wthi,
                                                  bq, bk, bv, qh, kh, vt);
  attn_kernel<<<dim3(16, NH, NB), 256, 0, stream>>>(qh, kh, vt, ah);
  out_gemm<<<dim3(16, 32, 1), 256, 0, stream>>>(ah, wthi, wtlo, bo, out);
}